// Round 11
// baseline (474.231 us; speedup 1.0000x reference)
//
#include <hip/hip_runtime.h>
#include <math.h>

// ---------------- problem constants ----------------
#define MB    512
#define FS    24
#define QDIM  11
#define OBJ   25
#define HID   256

typedef unsigned short u16;
typedef __attribute__((ext_vector_type(8))) __bf16 bf16x8;
typedef __attribute__((ext_vector_type(4))) __bf16 bf16x4;
typedef __attribute__((ext_vector_type(4))) float f32x4;
typedef __attribute__((ext_vector_type(8))) float f32x8;

__device__ __forceinline__ float bf2f(u16 h) {
    return __uint_as_float(((unsigned int)h) << 16);
}
__device__ __forceinline__ u16 f2bf(float f) {
    unsigned int u = __float_as_uint(f);
    return (u16)((u + 0x7FFFu + ((u >> 16) & 1u)) >> 16);
}

// ---------------- combined prep (+ stats/xg zeroing; replaces memset dispatch) ----------------
__global__ __launch_bounds__(256) void prep_all(
    const float* __restrict__ g2w, const float* __restrict__ g3w,
    const float* __restrict__ g4w, u16* __restrict__ wfrag,
    const float* __restrict__ cw1, const float* __restrict__ cw2,
    const float* __restrict__ cw3, const float* __restrict__ cw4,
    float* __restrict__ wt1, u16* __restrict__ wcfrag,
    float* __restrict__ stats, float* __restrict__ xg)
{
    // zeroing (consumers are in later dispatches; stream order guarantees visibility)
    if (blockIdx.x == 0 && threadIdx.x < 192) stats[threadIdx.x] = 0.f;
    if (blockIdx.x < 512) xg[blockIdx.x * 256 + threadIdx.x] = 0.f;

    if (blockIdx.x < 768) {
        int idx = blockIdx.x * 256 + threadIdx.x;   // 196608 total
        int jj = idx & 7;
        int lane = (idx >> 3) & 63;
        int tn = (idx >> 9) & 15;
        int c = (idx >> 13) & 7;
        int l = idx >> 16;
        const float* W = (l == 0) ? g2w : ((l == 1) ? g3w : g4w);
        int n = tn * 16 + (lane & 15);
        int k = c * 32 + (lane >> 4) * 8 + jj;
        wfrag[idx] = f2bf(W[n * 256 + k]);
    } else {
        int idx = (blockIdx.x - 768) * 256 + threadIdx.x;
        if (idx < 648) {
            int k = idx / 24, oc = idx % 24;
            wt1[idx] = cw1[oc * 27 + k];
        } else if (idx < 648 + 27648) {
            int t = idx - 648;
            int l = t / 9216, r = t % 9216;
            int cell = r / 1024, rr = r % 1024;
            int o = rr / 512, q = rr % 512;
            int lane = q / 8, j = q % 8;
            int oc = o * 16 + (lane & 15);
            int ic = (lane >> 4) * 8 + j;
            const float* w = (l == 0) ? cw2 : ((l == 1) ? cw3 : cw4);
            u16 v = 0;
            if (oc < 24 && ic < 24) v = f2bf(w[oc * 216 + ic * 9 + cell]);
            wcfrag[t] = v;
        }
    }
}

// ---------------- conv1: img NCHW -> y1 channel-last (bf16) + fused BN stats ----------------
__global__ __launch_bounds__(256) void conv1_t(
    const float* __restrict__ img, const float* __restrict__ wt1,
    const float* __restrict__ bias, u16* __restrict__ yout,
    float* __restrict__ stats)
{
    __shared__ float tile[3 * 21 * 85];
    __shared__ float part[48];
    const int tid = threadIdx.x;
    const int b   = blockIdx.x >> 2;
    const int y0  = (blockIdx.x & 3) * 10;
    const int iy_base = 2 * y0 - 1;
    for (int e = tid; e < 3 * 21 * 85; e += 256) {
        int ixt = e % 85; int rem = e / 85;
        int iyl = rem % 21; int ic = rem / 21;
        int iy = iy_base + iyl, ix = ixt - 1;
        float v = 0.f;
        if ((unsigned)iy < 80u && (unsigned)ix < 80u)
            v = img[((size_t)(b * 3 + ic) * 80 + iy) * 80 + ix];
        tile[e] = v;
    }
    if (tid < 48) part[tid] = 0.f;
    __syncthreads();

    float rsum[24], rsq[24];
#pragma unroll
    for (int oc = 0; oc < 24; oc++) { rsum[oc] = 0.f; rsq[oc] = 0.f; }

#pragma unroll 1
    for (int pp = 0; pp < 2; pp++) {
        const int pxl = tid + pp * 256;
        const bool active = pxl < 400;
        const int pxc = active ? pxl : 0;
        const int yl = pxc / 40, x = pxc % 40;
        float acc[24];
#pragma unroll
        for (int oc = 0; oc < 24; oc++) acc[oc] = bias[oc];
#pragma unroll 1
        for (int ic = 0; ic < 3; ic++) {
#pragma unroll 1
            for (int ky = 0; ky < 3; ky++) {
#pragma unroll 1
                for (int kx = 0; kx < 3; kx++) {
                    const int k = (ic * 3 + ky) * 3 + kx;
                    float xin = tile[ic * 1785 + (2 * yl + ky) * 85 + (2 * x + kx)];
                    const float4* wrow = (const float4*)&wt1[k * 24];
#pragma unroll
                    for (int g = 0; g < 6; g++) {
                        float4 wv = wrow[g];
                        acc[g * 4 + 0] = fmaf(xin, wv.x, acc[g * 4 + 0]);
                        acc[g * 4 + 1] = fmaf(xin, wv.y, acc[g * 4 + 1]);
                        acc[g * 4 + 2] = fmaf(xin, wv.z, acc[g * 4 + 2]);
                        acc[g * 4 + 3] = fmaf(xin, wv.w, acc[g * 4 + 3]);
                    }
                }
            }
        }
#pragma unroll
        for (int oc = 0; oc < 24; oc++)
            acc[oc] = active ? fmaxf(acc[oc], 0.f) : 0.f;
        if (active) {
            u16* op = &yout[((size_t)b * 1600 + (y0 + yl) * 40 + x) * 24];
#pragma unroll
            for (int g = 0; g < 3; g++) {
                f32x8 t = {acc[g * 8 + 0], acc[g * 8 + 1], acc[g * 8 + 2], acc[g * 8 + 3],
                           acc[g * 8 + 4], acc[g * 8 + 5], acc[g * 8 + 6], acc[g * 8 + 7]};
                bf16x8 hb = __builtin_convertvector(t, bf16x8);
                *(uint4*)&op[g * 8] = *(uint4*)&hb;
            }
        }
#pragma unroll
        for (int oc = 0; oc < 24; oc++) {
            rsum[oc] += acc[oc];
            rsq[oc]  += acc[oc] * acc[oc];
        }
    }

    // halving-tree wave reduction of 48 stats: 96 shfl.
    {
        float v[48];
#pragma unroll
        for (int oc = 0; oc < 24; oc++) { v[oc] = rsum[oc]; v[24 + oc] = rsq[oc]; }
        const int ln = tid & 63;
#pragma unroll
        for (int i = 0; i < 48; i++) v[i] += __shfl_xor(v[i], 1, 64);
        {
            const bool bs = (ln & 1) != 0;
#pragma unroll
            for (int i = 0; i < 24; i++) v[i] = bs ? v[24 + i] : v[i];
        }
#pragma unroll
        for (int i = 0; i < 24; i++) v[i] += __shfl_xor(v[i], 2, 64);
        {
            const bool bs = (ln & 2) != 0;
#pragma unroll
            for (int i = 0; i < 12; i++) v[i] = bs ? v[12 + i] : v[i];
        }
#pragma unroll
        for (int i = 0; i < 12; i++) v[i] += __shfl_xor(v[i], 4, 64);
        {
            const bool bs = (ln & 4) != 0;
#pragma unroll
            for (int i = 0; i < 6; i++) v[i] = bs ? v[6 + i] : v[i];
        }
#pragma unroll
        for (int i = 0; i < 6; i++) v[i] += __shfl_xor(v[i], 8, 64);
        {
            const bool bs = (ln & 8) != 0;
#pragma unroll
            for (int i = 0; i < 3; i++) v[i] = bs ? v[3 + i] : v[i];
        }
#pragma unroll
        for (int i = 0; i < 3; i++) {
            v[i] += __shfl_xor(v[i], 16, 64);
            v[i] += __shfl_xor(v[i], 32, 64);
        }
        if (ln < 16) {
            const int base = (ln & 1) * 24 + ((ln >> 1) & 1) * 12
                           + ((ln >> 2) & 1) * 6 + ((ln >> 3) & 1) * 3;
#pragma unroll
            for (int i = 0; i < 3; i++) atomicAdd(&part[base + i], v[i]);
        }
    }
    __syncthreads();
    if (tid < 48) atomicAdd(&stats[tid], part[tid]);
}

// ---------------- MFMA conv 24->24 stride2 pad1, channel-last, BN(prev) folded on read,
//                  bf16-in / bf16-out switchable, + fused bias/relu/store/BN-stats ----------------
template<int HIN, int HOUT, int YT, int MT, int INBF, int OUTBF>
__global__ __launch_bounds__(256) void convM(
    const void* __restrict__ yin,
    const float* __restrict__ stp, const float* __restrict__ gam,
    const float* __restrict__ bet, float invN,
    const u16* __restrict__ wcf_g,
    const float* __restrict__ bias,
    void* __restrict__ yout, float* __restrict__ stats)
{
    constexpr int ROWS = 2 * YT + 1;
    constexpr int R    = 2 * HOUT + 1;
    constexpr int POS  = ROWS * R;
    constexpr int NPX  = HOUT * HOUT;
    constexpr int NPXB = YT * HOUT;
    constexpr int TILES = HOUT / YT;
    constexpr int MTPW = (MT + 3) / 4;
    __shared__ __align__(16) u16 tile[POS * 24 + 16];
    __shared__ float scW[48];
    __shared__ float part[48];
    const int tid  = threadIdx.x;
    const int b    = (TILES == 1) ? blockIdx.x : (int)(blockIdx.x / TILES);
    const int y0   = (TILES == 1) ? 0 : (int)(blockIdx.x % TILES) * YT;
    const int lane = tid & 63, wave = tid >> 6;
    const int r16  = lane & 15, quad = lane >> 4;

    const float* yinF = (const float*)yin;
    const u16*   yinH = (const u16*)yin;
    float* yoF = (float*)yout;
    u16*   yoH = (u16*)yout;

    if (tid < 24) {
        float m   = stp[tid] * invN;
        float var = stp[24 + tid] * invN - m * m;
        float inv = gam[tid] * rsqrtf(var + 1e-5f);
        scW[tid]      = inv;
        scW[24 + tid] = bet[tid] - m * inv;
    }
    if (tid < 48) part[tid] = 0.f;

    // weight A-fragments -> registers (per lane)
    bf16x8 wcf[9][2];
#pragma unroll
    for (int c = 0; c < 9; c++)
#pragma unroll
        for (int o = 0; o < 2; o++)
            wcf[c][o] = *(const bf16x8*)&wcf_g[((c * 2 + o) * 64 + lane) * 8];

    __syncthreads();   // scW ready

    // hoist BN scale/shift to registers (vector form)
    f32x8 scv[3], ofv[3];
#pragma unroll
    for (int g = 0; g < 3; g++)
#pragma unroll
        for (int c2 = 0; c2 < 8; c2++) {
            scv[g][c2] = scW[g * 8 + c2];
            ofv[g][c2] = scW[24 + g * 8 + c2];
        }

    // stage input tile (bf16, channel-last, BN-folded)
    const int iy_base = 2 * y0 - 1;
    for (int p = tid; p < POS; p += 256) {
        int iyl = p / R, ixt = p % R;
        int iy = iy_base + iyl, ix = ixt - 1;
        if ((unsigned)iy < (unsigned)HIN && (unsigned)ix < (unsigned)HIN) {
            const size_t base = ((size_t)b * HIN * HIN + iy * HIN + ix) * 24;
            if constexpr (INBF) {
                const uint4* ip4 = (const uint4*)(yinH + base);
#pragma unroll
                for (int g = 0; g < 3; g++) {
                    uint4 raw = ip4[g];
                    bf16x8 hv = *(bf16x8*)&raw;
                    f32x8 xv = __builtin_convertvector(hv, f32x8);
                    f32x8 r = xv * scv[g] + ofv[g];
                    bf16x8 hb = __builtin_convertvector(r, bf16x8);
                    *(uint4*)&tile[p * 24 + g * 8] = *(uint4*)&hb;
                }
            } else {
                const float4* ip4 = (const float4*)(yinF + base);
#pragma unroll
                for (int g = 0; g < 3; g++) {
                    float4 A = ip4[g * 2], B = ip4[g * 2 + 1];
                    f32x8 xv = {A.x, A.y, A.z, A.w, B.x, B.y, B.z, B.w};
                    f32x8 r = xv * scv[g] + ofv[g];
                    bf16x8 hb = __builtin_convertvector(r, bf16x8);
                    *(uint4*)&tile[p * 24 + g * 8] = *(uint4*)&hb;
                }
            }
        } else {
            uint4 z = make_uint4(0, 0, 0, 0);
#pragma unroll
            for (int g = 0; g < 3; g++)
                *(uint4*)&tile[p * 24 + g * 8] = z;
        }
    }
    __syncthreads();

    f32x4 acc[MTPW][2];
#pragma unroll
    for (int t = 0; t < MTPW; t++) {
        acc[t][0] = (f32x4)(0.f);
        acc[t][1] = (f32x4)(0.f);
    }

    int baseT[MTPW];
#pragma unroll
    for (int t = 0; t < MTPW; t++) {
        int mt = wave + t * 4;
        int pxl = mt * 16 + r16;
        if (pxl > NPXB - 1) pxl = NPXB - 1;
        baseT[t] = ((2 * (pxl / HOUT)) * R + 2 * (pxl % HOUT)) * 24 + quad * 8;
    }

#pragma unroll
    for (int ky = 0; ky < 3; ky++) {
#pragma unroll
        for (int kx = 0; kx < 3; kx++) {
            const int cell = ky * 3 + kx;
            const int coff = (ky * R + kx) * 24;
            bf16x8 xf[MTPW];
#pragma unroll
            for (int t = 0; t < MTPW; t++) {
                int mt = wave + t * 4;
                uint4 tmp = make_uint4(0, 0, 0, 0);
                if (mt < MT && quad < 3)
                    tmp = *(const uint4*)&tile[baseT[t] + coff];
                xf[t] = *(bf16x8*)&tmp;
            }
#pragma unroll
            for (int t = 0; t < MTPW; t++) {
                int mt = wave + t * 4;
                if (mt < MT) {
                    acc[t][0] = __builtin_amdgcn_mfma_f32_16x16x32_bf16(
                        wcf[cell][0], xf[t], acc[t][0], 0, 0, 0);
                    acc[t][1] = __builtin_amdgcn_mfma_f32_16x16x32_bf16(
                        wcf[cell][1], xf[t], acc[t][1], 0, 0, 0);
                }
            }
        }
    }

    // epilogue: bias + relu + store + stats
    float ss[2][4], qq[2][4];
#pragma unroll
    for (int o = 0; o < 2; o++)
#pragma unroll
        for (int r = 0; r < 4; r++) { ss[o][r] = 0.f; qq[o][r] = 0.f; }

#pragma unroll
    for (int t = 0; t < MTPW; t++) {
        int mt = wave + t * 4;
        if (mt >= MT) continue;
        int pxl = mt * 16 + r16;
        bool pv = pxl < NPXB;
        int pxi = y0 * HOUT + pxl;
#pragma unroll
        for (int o = 0; o < 2; o++) {
            int ocb = o * 16 + quad * 4;
            if (pv && ocb < 24) {
                float4 bb = *(const float4*)&bias[ocb];
                float v0 = fmaxf(acc[t][o][0] + bb.x, 0.f);
                float v1 = fmaxf(acc[t][o][1] + bb.y, 0.f);
                float v2 = fmaxf(acc[t][o][2] + bb.z, 0.f);
                float v3 = fmaxf(acc[t][o][3] + bb.w, 0.f);
                if constexpr (OUTBF) {
                    f32x4 tv = {v0, v1, v2, v3};
                    bf16x4 hb = __builtin_convertvector(tv, bf16x4);
                    *(ushort4*)&yoH[((size_t)b * NPX + pxi) * 24 + ocb] = *(ushort4*)&hb;
                } else {
                    *(float4*)&yoF[((size_t)b * NPX + pxi) * 24 + ocb] =
                        make_float4(v0, v1, v2, v3);
                }
                ss[o][0] += v0; qq[o][0] += v0 * v0;
                ss[o][1] += v1; qq[o][1] += v1 * v1;
                ss[o][2] += v2; qq[o][2] += v2 * v2;
                ss[o][3] += v3; qq[o][3] += v3 * v3;
            }
        }
    }
#pragma unroll
    for (int o = 0; o < 2; o++) {
        int ocb = o * 16 + quad * 4;
#pragma unroll
        for (int r = 0; r < 4; r++) {
            float a = ss[o][r], q = qq[o][r];
            a += __shfl_xor(a, 1, 64); q += __shfl_xor(q, 1, 64);
            a += __shfl_xor(a, 2, 64); q += __shfl_xor(q, 2, 64);
            a += __shfl_xor(a, 4, 64); q += __shfl_xor(q, 4, 64);
            a += __shfl_xor(a, 8, 64); q += __shfl_xor(q, 8, 64);
            if (r16 == 0 && ocb < 24) {
                atomicAdd(&part[ocb + r], a);
                atomicAdd(&part[24 + ocb + r], q);
            }
        }
    }
    __syncthreads();
    if (tid < 48) atomicAdd(&stats[tid], part[tid]);
}

// ---------------- u/v precompute for g1 (bf16 output), BN4 computed in-kernel ----------------
__global__ __launch_bounds__(256) void uv_kernel(
    const float* __restrict__ y4t,
    const float* __restrict__ stp, const float* __restrict__ gam,
    const float* __restrict__ bet, float invN,
    const float* __restrict__ qst, const float* __restrict__ g1w,
    const float* __restrict__ g1b, u16* __restrict__ u, u16* __restrict__ v)
{
    int b = blockIdx.x, tid = threadIdx.x;
    __shared__ float xf[650];
    __shared__ float qv[11];
    __shared__ float scW[48];
    if (tid < 24) {
        float m   = stp[tid] * invN;
        float var = stp[24 + tid] * invN - m * m;
        float inv = gam[tid] * rsqrtf(var + 1e-5f);
        scW[tid]      = inv;
        scW[24 + tid] = bet[tid] - m * inv;
    }
    __syncthreads();
    for (int e = tid; e < 650; e += 256) {
        int o = e / 26, c = e % 26;
        float val;
        if (c < 24)      val = y4t[b * 600 + o * 24 + c] * scW[c] + scW[24 + c];
        else if (c == 24) val = (float)(o / 5 - 2) * 0.5f;
        else              val = (float)(o % 5 - 2) * 0.5f;
        xf[e] = val;
    }
    if (tid < 11) qv[tid] = qst[tid * MB + b];
    __syncthreads();
    const int n = tid;
    float wrow[63];
#pragma unroll
    for (int c = 0; c < 63; c++) wrow[c] = g1w[n * 63 + c];
    float qsum = g1b[n];
#pragma unroll
    for (int j = 0; j < 11; j++) qsum += wrow[52 + j] * qv[j];
    for (int o = 0; o < 25; o++) {
        float uu = 0.f, vv = qsum;
#pragma unroll
        for (int c = 0; c < 26; c++) {
            uu += wrow[c]      * xf[o * 26 + c];
            vv += wrow[26 + c] * xf[o * 26 + c];
        }
        u[(b * 25 + o) * 256 + n] = f2bf(uu);
        v[(b * 25 + o) * 256 + n] = f2bf(vv);
    }
}

// ---------------- fused g2/g3/g4 + pair-sum, bf16 MFMA; one 128-row pair-chunk per dispatch ----------------
__global__ __launch_bounds__(256, 2) void g_fused(
    const u16* __restrict__ u_bf, const u16* __restrict__ v_bf,
    const u16* __restrict__ wfrag,
    const float* __restrict__ b2, const float* __restrict__ b3, const float* __restrict__ b4,
    float* __restrict__ xg, int chunk)
{
    __shared__ u16 hS[32768];   // 128 x 256 halves, XOR-swizzled 8-half granules
    const int tid  = threadIdx.x;
    const int b    = blockIdx.x;
    const int p0   = chunk * 128;
    const int lane = tid & 63, wave = tid >> 6;
    const int r16  = lane & 15, sub = lane >> 4;
    const int n0w  = wave * 64;

    const u16* wfL = wfrag + (size_t)(wave * 4) * 512 + (size_t)lane * 8;

    bf16x8 wcur[4], wnxt[4];
#pragma unroll
    for (int tn = 0; tn < 4; tn++)
        wcur[tn] = *(const bf16x8*)&wfL[(size_t)tn * 512];
#pragma unroll
    for (int tn = 0; tn < 4; tn++) wnxt[tn] = wcur[tn];

    {
        const int m = tid & 127, half = tid >> 7;
        const int p = p0 + m;
        if (p < 625) {
            const int oi = p % 25, ok = p / 25;
            const uint4* up = (const uint4*)(u_bf + (size_t)(b * 25 + oi) * 256);
            const uint4* vp = (const uint4*)(v_bf + (size_t)(b * 25 + ok) * 256);
#pragma unroll
            for (int gi = 0; gi < 16; gi++) {
                const int g = half * 16 + gi;
                uint4 ua = up[g], va = vp[g];
                bf16x8 ub = *(bf16x8*)&ua;
                bf16x8 vb = *(bf16x8*)&va;
                f32x8 uf = __builtin_convertvector(ub, f32x8);
                f32x8 vf = __builtin_convertvector(vb, f32x8);
                f32x8 hf = uf + vf;
                hf = __builtin_elementwise_max(hf, (f32x8)(0.f));
                bf16x8 hb = __builtin_convertvector(hf, bf16x8);
                *(uint4*)&hS[m * 256 + ((g ^ (m & 7)) * 8)] = *(uint4*)&hb;
            }
        } else {
            uint4 z = make_uint4(0, 0, 0, 0);
#pragma unroll
            for (int gi = 0; gi < 16; gi++) {
                const int g = half * 16 + gi;
                *(uint4*)&hS[m * 256 + ((g ^ (m & 7)) * 8)] = z;
            }
        }
    }

#pragma unroll 1
    for (int l = 0; l < 3; l++) {
        f32x4 acc[8][4];
#pragma unroll
        for (int tm = 0; tm < 8; tm++)
#pragma unroll
            for (int tn = 0; tn < 4; tn++)
                acc[tm][tn] = (f32x4)(0.f);

        __syncthreads();

#pragma unroll 1
        for (int kb = 0; kb < 8; kb++) {
            const int s = l * 8 + kb;
            if (s < 23) {
#pragma unroll
                for (int tn = 0; tn < 4; tn++)
                    wnxt[tn] = *(const bf16x8*)&wfL[((size_t)(s + 1) * 16 + tn) * 512];
            }
            bf16x8 bfr[8];
            const int g = kb * 4 + sub;
#pragma unroll
            for (int tm = 0; tm < 8; tm++) {
                const int m = tm * 16 + r16;
                bfr[tm] = *(const bf16x8*)&hS[m * 256 + ((g ^ (m & 7)) * 8)];
            }
#pragma unroll
            for (int tm = 0; tm < 8; tm++)
#pragma unroll
                for (int tn = 0; tn < 4; tn++)
                    acc[tm][tn] = __builtin_amdgcn_mfma_f32_16x16x32_bf16(
                        wcur[tn], bfr[tm], acc[tm][tn], 0, 0, 0);
#pragma unroll
            for (int tn = 0; tn < 4; tn++) wcur[tn] = wnxt[tn];
        }
        __syncthreads();

        const float* bl = (l == 0) ? b2 : ((l == 1) ? b3 : b4);
        if (l < 2) {
#pragma unroll
            for (int tn = 0; tn < 4; tn++) {
                const int n0 = n0w + tn * 16 + sub * 4;
                const float4 bb = *(const float4*)&bl[n0];
                const f32x4 bb4 = {bb.x, bb.y, bb.z, bb.w};
                const int gg = n0 >> 3;
                const int sh = (sub & 1) * 4;
#pragma unroll
                for (int tm = 0; tm < 8; tm++) {
                    const int m = tm * 16 + r16;
                    f32x4 t = acc[tm][tn] + bb4;
                    t = __builtin_elementwise_max(t, (f32x4)(0.f));
                    bf16x4 hb = __builtin_convertvector(t, bf16x4);
                    *(ushort4*)&hS[m * 256 + ((gg ^ (m & 7)) * 8) + sh] = *(ushort4*)&hb;
                }
            }
        } else {
            f32x4 sv[4];
#pragma unroll
            for (int tn = 0; tn < 4; tn++) sv[tn] = (f32x4)(0.f);
#pragma unroll
            for (int tn = 0; tn < 4; tn++) {
                const int n0 = n0w + tn * 16 + sub * 4;
                const float4 bb = *(const float4*)&bl[n0];
                const f32x4 bb4 = {bb.x, bb.y, bb.z, bb.w};
#pragma unroll
                for (int tm = 0; tm < 8; tm++) {
                    const int m = tm * 16 + r16;
                    if (p0 + m < 625) {
                        f32x4 t = acc[tm][tn] + bb4;
                        t = __builtin_elementwise_max(t, (f32x4)(0.f));
                        sv[tn] += t;
                    }
                }
            }
#pragma unroll
            for (int tn = 0; tn < 4; tn++)
#pragma unroll
                for (int r = 0; r < 4; r++) {
                    float v = sv[tn][r];
                    v += __shfl_xor(v, 1, 64);
                    v += __shfl_xor(v, 2, 64);
                    v += __shfl_xor(v, 4, 64);
                    v += __shfl_xor(v, 8, 64);
                    if (r16 == 0)
                        atomicAdd(&xg[b * 256 + n0w + tn * 16 + sub * 4 + r], v);
                }
        }
    }
}

// ---------------- f1 -> fc2 -> fc3 -> log_softmax ----------------
__global__ __launch_bounds__(256) void f_fused(
    const float* __restrict__ xg,
    const float* __restrict__ f1w, const float* __restrict__ f1b,
    const float* __restrict__ fc2w, const float* __restrict__ fc2b,
    const float* __restrict__ fc3w, const float* __restrict__ fc3b,
    float* __restrict__ out)
{
    const int b = blockIdx.x, tid = threadIdx.x;
    __shared__ float xa[256], xb[256], lg[10], red[2];
    xa[tid] = xg[b * 256 + tid];
    __syncthreads();
    {
        const float4* wr = (const float4*)(f1w + (size_t)tid * 256);
        float a = f1b[tid];
#pragma unroll
        for (int k4 = 0; k4 < 64; k4++) {
            float4 w4 = wr[k4];
            a += w4.x * xa[k4 * 4 + 0] + w4.y * xa[k4 * 4 + 1]
               + w4.z * xa[k4 * 4 + 2] + w4.w * xa[k4 * 4 + 3];
        }
        xb[tid] = a > 0.f ? a : 0.f;
    }
    __syncthreads();
    {
        const float4* wr = (const float4*)(fc2w + (size_t)tid * 256);
        float a = fc2b[tid];
#pragma unroll
        for (int k4 = 0; k4 < 64; k4++) {
            float4 w4 = wr[k4];
            a += w4.x * xb[k4 * 4 + 0] + w4.y * xb[k4 * 4 + 1]
               + w4.z * xb[k4 * 4 + 2] + w4.w * xb[k4 * 4 + 3];
        }
        __syncthreads();
        xa[tid] = a > 0.f ? a : 0.f;
    }
    __syncthreads();
    if (tid < 10) {
        const float4* wr = (const float4*)(fc3w + (size_t)tid * 256);
        float a = fc3b[tid];
#pragma unroll
        for (int k4 = 0; k4 < 64; k4++) {
            float4 w4 = wr[k4];
            a += w4.x * xa[k4 * 4 + 0] + w4.y * xa[k4 * 4 + 1]
               + w4.z * xa[k4 * 4 + 2] + w4.w * xa[k4 * 4 + 3];
        }
        lg[tid] = a;
    }
    __syncthreads();
    if (tid == 0) {
        float mx = lg[0];
        for (int o = 1; o < 10; o++) mx = lg[o] > mx ? lg[o] : mx;
        float ssum = 0.f;
        for (int o = 0; o < 10; o++) ssum += expf(lg[o] - mx);
        red[0] = mx;
        red[1] = logf(ssum);
    }
    __syncthreads();
    if (tid < 10) out[b * 10 + tid] = lg[tid] - red[0] - red[1];
}

// ---------------- launcher ----------------
extern "C" void kernel_launch(void* const* d_in, const int* in_sizes, int n_in,
                              void* d_out, int out_size, void* d_ws, size_t ws_size,
                              hipStream_t stream)
{
    const float* img  = (const float*)d_in[0];
    const float* qst  = (const float*)d_in[1];
    const float* cw1  = (const float*)d_in[2];
    const float* cb1  = (const float*)d_in[3];
    const float* bg1  = (const float*)d_in[4];
    const float* bb1  = (const float*)d_in[5];
    const float* cw2  = (const float*)d_in[6];
    const float* cb2  = (const float*)d_in[7];
    const float* bg2  = (const float*)d_in[8];
    const float* bb2  = (const float*)d_in[9];
    const float* cw3  = (const float*)d_in[10];
    const float* cb3  = (const float*)d_in[11];
    const float* bg3  = (const float*)d_in[12];
    const float* bb3  = (const float*)d_in[13];
    const float* cw4  = (const float*)d_in[14];
    const float* cb4  = (const float*)d_in[15];
    const float* bg4  = (const float*)d_in[16];
    const float* bb4  = (const float*)d_in[17];
    const float* g1w  = (const float*)d_in[18];
    const float* g1b  = (const float*)d_in[19];
    const float* g2w  = (const float*)d_in[20];
    const float* g2b  = (const float*)d_in[21];
    const float* g3w  = (const float*)d_in[22];
    const float* g3b  = (const float*)d_in[23];
    const float* g4w  = (const float*)d_in[24];
    const float* g4b  = (const float*)d_in[25];
    const float* f1w  = (const float*)d_in[26];
    const float* f1b  = (const float*)d_in[27];
    const float* fc2w = (const float*)d_in[28];
    const float* fc2b = (const float*)d_in[29];
    const float* fc3w = (const float*)d_in[30];
    const float* fc3b = (const float*)d_in[31];
    float* out = (float*)d_out;

    float* ws    = (float*)d_ws;
    float* stats = ws;                        // 192
    float* xg    = ws + 192;                  // 131072
    u16*   wfrag = (u16*)(ws + 131456);       // 196608 u16
    u16*   y1u   = (u16*)(ws + 328064);       // 19,660,800 u16 (bf16)
    u16*   y2u   = (u16*)(ws + 19988864);     // 4,915,200 u16 (bf16)
    float* y3    = ws + 24904064;             // 1,228,800   [b][100][24]
    float* y4    = ws + 26132864;             // 307,200     [b][25][24]
    u16*   u_bf  = (u16*)(ws + 26440064);     // 3,276,800 u16
    u16*   v_bf  = (u16*)(ws + 28078464);     // 3,276,800 u16
    float* wt1   = ws + 29716864;             // 648
    u16*   wcfrag = (u16*)(ws + 29717512);    // 27648 u16

    prep_all<<<879, 256, 0, stream>>>(g2w, g3w, g4w, wfrag,
                                      cw1, cw2, cw3, cw4, wt1, wcfrag,
                                      stats, xg);

    conv1_t<<<2048, 256, 0, stream>>>(img, wt1, cb1, y1u, stats);

    convM<40, 20, 4, 5, 1, 1><<<2560, 256, 0, stream>>>(
        (const void*)y1u, stats, bg1, bb1, 1.f / 819200.f, wcfrag, cb2,
        (void*)y2u, stats + 48);
    convM<20, 10, 10, 7, 1, 0><<<512, 256, 0, stream>>>(
        (const void*)y2u, stats + 48, bg2, bb2, 1.f / 204800.f, wcfrag + 9216, cb3,
        (void*)y3, stats + 96);
    convM<10, 5, 5, 2, 0, 0><<<512, 256, 0, stream>>>(
        (const void*)y3, stats + 96, bg3, bb3, 1.f / 51200.f, wcfrag + 18432, cb4,
        (void*)y4, stats + 144);

    uv_kernel<<<512, 256, 0, stream>>>(y4, stats + 144, bg4, bb4, 1.f / 12800.f,
                                       qst, g1w, g1b, u_bf, v_bf);

    for (int chunk = 0; chunk < 5; chunk++)
        g_fused<<<512, 256, 0, stream>>>(u_bf, v_bf, wfrag, g2b, g3b, g4b, xg, chunk);

    f_fused<<<512, 256, 0, stream>>>(xg, f1w, f1b, fc2w, fc2b, fc3w, fc3b, out);
}

// Round 12
// 446.631 us; speedup vs baseline: 1.0618x; 1.0618x over previous
//
#include <hip/hip_runtime.h>
#include <math.h>

// ---------------- problem constants ----------------
#define MB    512
#define FS    24
#define QDIM  11
#define OBJ   25
#define HID   256

typedef unsigned short u16;
typedef __attribute__((ext_vector_type(8))) __bf16 bf16x8;
typedef __attribute__((ext_vector_type(4))) __bf16 bf16x4;
typedef __attribute__((ext_vector_type(4))) float f32x4;
typedef __attribute__((ext_vector_type(8))) float f32x8;

__device__ __forceinline__ float bf2f(u16 h) {
    return __uint_as_float(((unsigned int)h) << 16);
}
__device__ __forceinline__ u16 f2bf(float f) {
    unsigned int u = __float_as_uint(f);
    return (u16)((u + 0x7FFFu + ((u >> 16) & 1u)) >> 16);
}

// ---------------- combined prep (+ stats/xg zeroing; replaces memset dispatch) ----------------
__global__ __launch_bounds__(256) void prep_all(
    const float* __restrict__ g2w, const float* __restrict__ g3w,
    const float* __restrict__ g4w, u16* __restrict__ wfrag,
    const float* __restrict__ cw1, const float* __restrict__ cw2,
    const float* __restrict__ cw3, const float* __restrict__ cw4,
    float* __restrict__ wt1, u16* __restrict__ wcfrag,
    float* __restrict__ stats, float* __restrict__ xg)
{
    // zeroing (consumers are in later dispatches; stream order guarantees visibility)
    if (blockIdx.x == 0 && threadIdx.x < 192) stats[threadIdx.x] = 0.f;
    if (blockIdx.x < 512) xg[blockIdx.x * 256 + threadIdx.x] = 0.f;

    if (blockIdx.x < 768) {
        int idx = blockIdx.x * 256 + threadIdx.x;   // 196608 total
        int jj = idx & 7;
        int lane = (idx >> 3) & 63;
        int tn = (idx >> 9) & 15;
        int c = (idx >> 13) & 7;
        int l = idx >> 16;
        const float* W = (l == 0) ? g2w : ((l == 1) ? g3w : g4w);
        int n = tn * 16 + (lane & 15);
        int k = c * 32 + (lane >> 4) * 8 + jj;
        wfrag[idx] = f2bf(W[n * 256 + k]);
    } else {
        int idx = (blockIdx.x - 768) * 256 + threadIdx.x;
        if (idx < 648) {
            int k = idx / 24, oc = idx % 24;
            wt1[idx] = cw1[oc * 27 + k];
        } else if (idx < 648 + 27648) {
            int t = idx - 648;
            int l = t / 9216, r = t % 9216;
            int cell = r / 1024, rr = r % 1024;
            int o = rr / 512, q = rr % 512;
            int lane = q / 8, j = q % 8;
            int oc = o * 16 + (lane & 15);
            int ic = (lane >> 4) * 8 + j;
            const float* w = (l == 0) ? cw2 : ((l == 1) ? cw3 : cw4);
            u16 v = 0;
            if (oc < 24 && ic < 24) v = f2bf(w[oc * 216 + ic * 9 + cell]);
            wcfrag[t] = v;
        }
    }
}

// ---------------- conv1: img NCHW -> y1 channel-last (bf16) + fused BN stats.
// Two pixels per thread per k-cell: each weight float4 feeds 8 FMAs (was 4). ----------------
__global__ __launch_bounds__(256) void conv1_t(
    const float* __restrict__ img, const float* __restrict__ wt1,
    const float* __restrict__ bias, u16* __restrict__ yout,
    float* __restrict__ stats)
{
    __shared__ float tile[3 * 21 * 85];
    __shared__ float part[48];
    const int tid = threadIdx.x;
    const int b   = blockIdx.x >> 2;
    const int y0  = (blockIdx.x & 3) * 10;
    const int iy_base = 2 * y0 - 1;
    for (int e = tid; e < 3 * 21 * 85; e += 256) {
        int ixt = e % 85; int rem = e / 85;
        int iyl = rem % 21; int ic = rem / 21;
        int iy = iy_base + iyl, ix = ixt - 1;
        float v = 0.f;
        if ((unsigned)iy < 80u && (unsigned)ix < 80u)
            v = img[((size_t)(b * 3 + ic) * 80 + iy) * 80 + ix];
        tile[e] = v;
    }
    if (tid < 48) part[tid] = 0.f;
    __syncthreads();

    // pixel 0: tid (always < 400); pixel 1: tid + 256 (active if tid < 144)
    const int px0 = tid;
    const bool act1 = tid < 144;
    const int px1 = act1 ? (tid + 256) : tid;
    const int yl0 = px0 / 40, x0 = px0 % 40;
    const int yl1 = px1 / 40, x1 = px1 % 40;

    float acc0[24], acc1[24];
#pragma unroll
    for (int oc = 0; oc < 24; oc++) { acc0[oc] = bias[oc]; acc1[oc] = acc0[oc]; }

#pragma unroll 1
    for (int ic = 0; ic < 3; ic++) {
#pragma unroll 1
        for (int ky = 0; ky < 3; ky++) {
#pragma unroll
            for (int kx = 0; kx < 3; kx++) {
                const int k = (ic * 3 + ky) * 3 + kx;
                float xin0 = tile[ic * 1785 + (2 * yl0 + ky) * 85 + (2 * x0 + kx)];
                float xin1 = tile[ic * 1785 + (2 * yl1 + ky) * 85 + (2 * x1 + kx)];
                const float4* wrow = (const float4*)&wt1[k * 24];
#pragma unroll
                for (int g = 0; g < 6; g++) {
                    float4 wv = wrow[g];
                    acc0[g * 4 + 0] = fmaf(xin0, wv.x, acc0[g * 4 + 0]);
                    acc0[g * 4 + 1] = fmaf(xin0, wv.y, acc0[g * 4 + 1]);
                    acc0[g * 4 + 2] = fmaf(xin0, wv.z, acc0[g * 4 + 2]);
                    acc0[g * 4 + 3] = fmaf(xin0, wv.w, acc0[g * 4 + 3]);
                    acc1[g * 4 + 0] = fmaf(xin1, wv.x, acc1[g * 4 + 0]);
                    acc1[g * 4 + 1] = fmaf(xin1, wv.y, acc1[g * 4 + 1]);
                    acc1[g * 4 + 2] = fmaf(xin1, wv.z, acc1[g * 4 + 2]);
                    acc1[g * 4 + 3] = fmaf(xin1, wv.w, acc1[g * 4 + 3]);
                }
            }
        }
    }

#pragma unroll
    for (int oc = 0; oc < 24; oc++) {
        acc0[oc] = fmaxf(acc0[oc], 0.f);
        acc1[oc] = act1 ? fmaxf(acc1[oc], 0.f) : 0.f;
    }
    {
        u16* op = &yout[((size_t)b * 1600 + (y0 + yl0) * 40 + x0) * 24];
#pragma unroll
        for (int g = 0; g < 3; g++) {
            f32x8 t = {acc0[g * 8 + 0], acc0[g * 8 + 1], acc0[g * 8 + 2], acc0[g * 8 + 3],
                       acc0[g * 8 + 4], acc0[g * 8 + 5], acc0[g * 8 + 6], acc0[g * 8 + 7]};
            bf16x8 hb = __builtin_convertvector(t, bf16x8);
            *(uint4*)&op[g * 8] = *(uint4*)&hb;
        }
    }
    if (act1) {
        u16* op = &yout[((size_t)b * 1600 + (y0 + yl1) * 40 + x1) * 24];
#pragma unroll
        for (int g = 0; g < 3; g++) {
            f32x8 t = {acc1[g * 8 + 0], acc1[g * 8 + 1], acc1[g * 8 + 2], acc1[g * 8 + 3],
                       acc1[g * 8 + 4], acc1[g * 8 + 5], acc1[g * 8 + 6], acc1[g * 8 + 7]};
            bf16x8 hb = __builtin_convertvector(t, bf16x8);
            *(uint4*)&op[g * 8] = *(uint4*)&hb;
        }
    }

    // halving-tree wave reduction of 48 stats: 96 shfl.
    {
        float v[48];
#pragma unroll
        for (int oc = 0; oc < 24; oc++) {
            v[oc] = acc0[oc] + acc1[oc];
            v[24 + oc] = acc0[oc] * acc0[oc] + acc1[oc] * acc1[oc];
        }
        const int ln = tid & 63;
#pragma unroll
        for (int i = 0; i < 48; i++) v[i] += __shfl_xor(v[i], 1, 64);
        {
            const bool bs = (ln & 1) != 0;
#pragma unroll
            for (int i = 0; i < 24; i++) v[i] = bs ? v[24 + i] : v[i];
        }
#pragma unroll
        for (int i = 0; i < 24; i++) v[i] += __shfl_xor(v[i], 2, 64);
        {
            const bool bs = (ln & 2) != 0;
#pragma unroll
            for (int i = 0; i < 12; i++) v[i] = bs ? v[12 + i] : v[i];
        }
#pragma unroll
        for (int i = 0; i < 12; i++) v[i] += __shfl_xor(v[i], 4, 64);
        {
            const bool bs = (ln & 4) != 0;
#pragma unroll
            for (int i = 0; i < 6; i++) v[i] = bs ? v[6 + i] : v[i];
        }
#pragma unroll
        for (int i = 0; i < 6; i++) v[i] += __shfl_xor(v[i], 8, 64);
        {
            const bool bs = (ln & 8) != 0;
#pragma unroll
            for (int i = 0; i < 3; i++) v[i] = bs ? v[3 + i] : v[i];
        }
#pragma unroll
        for (int i = 0; i < 3; i++) {
            v[i] += __shfl_xor(v[i], 16, 64);
            v[i] += __shfl_xor(v[i], 32, 64);
        }
        if (ln < 16) {
            const int base = (ln & 1) * 24 + ((ln >> 1) & 1) * 12
                           + ((ln >> 2) & 1) * 6 + ((ln >> 3) & 1) * 3;
#pragma unroll
            for (int i = 0; i < 3; i++) atomicAdd(&part[base + i], v[i]);
        }
    }
    __syncthreads();
    if (tid < 48) atomicAdd(&stats[tid], part[tid]);
}

// ---------------- MFMA conv 24->24 stride2 pad1, channel-last, BN(prev) folded on read,
//                  bf16-in / bf16-out switchable, + fused bias/relu/store/BN-stats ----------------
template<int HIN, int HOUT, int YT, int MT, int INBF, int OUTBF>
__global__ __launch_bounds__(256) void convM(
    const void* __restrict__ yin,
    const float* __restrict__ stp, const float* __restrict__ gam,
    const float* __restrict__ bet, float invN,
    const u16* __restrict__ wcf_g,
    const float* __restrict__ bias,
    void* __restrict__ yout, float* __restrict__ stats)
{
    constexpr int ROWS = 2 * YT + 1;
    constexpr int R    = 2 * HOUT + 1;
    constexpr int POS  = ROWS * R;
    constexpr int NPX  = HOUT * HOUT;
    constexpr int NPXB = YT * HOUT;
    constexpr int TILES = HOUT / YT;
    constexpr int MTPW = (MT + 3) / 4;
    __shared__ __align__(16) u16 tile[POS * 24 + 16];
    __shared__ float scW[48];
    __shared__ float part[48];
    const int tid  = threadIdx.x;
    const int b    = (TILES == 1) ? blockIdx.x : (int)(blockIdx.x / TILES);
    const int y0   = (TILES == 1) ? 0 : (int)(blockIdx.x % TILES) * YT;
    const int lane = tid & 63, wave = tid >> 6;
    const int r16  = lane & 15, quad = lane >> 4;

    const float* yinF = (const float*)yin;
    const u16*   yinH = (const u16*)yin;
    float* yoF = (float*)yout;
    u16*   yoH = (u16*)yout;

    if (tid < 24) {
        float m   = stp[tid] * invN;
        float var = stp[24 + tid] * invN - m * m;
        float inv = gam[tid] * rsqrtf(var + 1e-5f);
        scW[tid]      = inv;
        scW[24 + tid] = bet[tid] - m * inv;
    }
    if (tid < 48) part[tid] = 0.f;

    // weight A-fragments -> registers (per lane)
    bf16x8 wcf[9][2];
#pragma unroll
    for (int c = 0; c < 9; c++)
#pragma unroll
        for (int o = 0; o < 2; o++)
            wcf[c][o] = *(const bf16x8*)&wcf_g[((c * 2 + o) * 64 + lane) * 8];

    __syncthreads();   // scW ready

    // hoist BN scale/shift to registers (vector form)
    f32x8 scv[3], ofv[3];
#pragma unroll
    for (int g = 0; g < 3; g++)
#pragma unroll
        for (int c2 = 0; c2 < 8; c2++) {
            scv[g][c2] = scW[g * 8 + c2];
            ofv[g][c2] = scW[24 + g * 8 + c2];
        }

    // stage input tile (bf16, channel-last, BN-folded)
    const int iy_base = 2 * y0 - 1;
    for (int p = tid; p < POS; p += 256) {
        int iyl = p / R, ixt = p % R;
        int iy = iy_base + iyl, ix = ixt - 1;
        if ((unsigned)iy < (unsigned)HIN && (unsigned)ix < (unsigned)HIN) {
            const size_t base = ((size_t)b * HIN * HIN + iy * HIN + ix) * 24;
            if constexpr (INBF) {
                const uint4* ip4 = (const uint4*)(yinH + base);
#pragma unroll
                for (int g = 0; g < 3; g++) {
                    uint4 raw = ip4[g];
                    bf16x8 hv = *(bf16x8*)&raw;
                    f32x8 xv = __builtin_convertvector(hv, f32x8);
                    f32x8 r = xv * scv[g] + ofv[g];
                    bf16x8 hb = __builtin_convertvector(r, bf16x8);
                    *(uint4*)&tile[p * 24 + g * 8] = *(uint4*)&hb;
                }
            } else {
                const float4* ip4 = (const float4*)(yinF + base);
#pragma unroll
                for (int g = 0; g < 3; g++) {
                    float4 A = ip4[g * 2], B = ip4[g * 2 + 1];
                    f32x8 xv = {A.x, A.y, A.z, A.w, B.x, B.y, B.z, B.w};
                    f32x8 r = xv * scv[g] + ofv[g];
                    bf16x8 hb = __builtin_convertvector(r, bf16x8);
                    *(uint4*)&tile[p * 24 + g * 8] = *(uint4*)&hb;
                }
            }
        } else {
            uint4 z = make_uint4(0, 0, 0, 0);
#pragma unroll
            for (int g = 0; g < 3; g++)
                *(uint4*)&tile[p * 24 + g * 8] = z;
        }
    }
    __syncthreads();

    f32x4 acc[MTPW][2];
#pragma unroll
    for (int t = 0; t < MTPW; t++) {
        acc[t][0] = (f32x4)(0.f);
        acc[t][1] = (f32x4)(0.f);
    }

    int baseT[MTPW];
#pragma unroll
    for (int t = 0; t < MTPW; t++) {
        int mt = wave + t * 4;
        int pxl = mt * 16 + r16;
        if (pxl > NPXB - 1) pxl = NPXB - 1;
        baseT[t] = ((2 * (pxl / HOUT)) * R + 2 * (pxl % HOUT)) * 24 + quad * 8;
    }

#pragma unroll
    for (int ky = 0; ky < 3; ky++) {
#pragma unroll
        for (int kx = 0; kx < 3; kx++) {
            const int cell = ky * 3 + kx;
            const int coff = (ky * R + kx) * 24;
            bf16x8 xf[MTPW];
#pragma unroll
            for (int t = 0; t < MTPW; t++) {
                int mt = wave + t * 4;
                uint4 tmp = make_uint4(0, 0, 0, 0);
                if (mt < MT && quad < 3)
                    tmp = *(const uint4*)&tile[baseT[t] + coff];
                xf[t] = *(bf16x8*)&tmp;
            }
#pragma unroll
            for (int t = 0; t < MTPW; t++) {
                int mt = wave + t * 4;
                if (mt < MT) {
                    acc[t][0] = __builtin_amdgcn_mfma_f32_16x16x32_bf16(
                        wcf[cell][0], xf[t], acc[t][0], 0, 0, 0);
                    acc[t][1] = __builtin_amdgcn_mfma_f32_16x16x32_bf16(
                        wcf[cell][1], xf[t], acc[t][1], 0, 0, 0);
                }
            }
        }
    }

    // epilogue: bias + relu + store + stats
    float ss[2][4], qq[2][4];
#pragma unroll
    for (int o = 0; o < 2; o++)
#pragma unroll
        for (int r = 0; r < 4; r++) { ss[o][r] = 0.f; qq[o][r] = 0.f; }

#pragma unroll
    for (int t = 0; t < MTPW; t++) {
        int mt = wave + t * 4;
        if (mt >= MT) continue;
        int pxl = mt * 16 + r16;
        bool pv = pxl < NPXB;
        int pxi = y0 * HOUT + pxl;
#pragma unroll
        for (int o = 0; o < 2; o++) {
            int ocb = o * 16 + quad * 4;
            if (pv && ocb < 24) {
                float4 bb = *(const float4*)&bias[ocb];
                float v0 = fmaxf(acc[t][o][0] + bb.x, 0.f);
                float v1 = fmaxf(acc[t][o][1] + bb.y, 0.f);
                float v2 = fmaxf(acc[t][o][2] + bb.z, 0.f);
                float v3 = fmaxf(acc[t][o][3] + bb.w, 0.f);
                if constexpr (OUTBF) {
                    f32x4 tv = {v0, v1, v2, v3};
                    bf16x4 hb = __builtin_convertvector(tv, bf16x4);
                    *(ushort4*)&yoH[((size_t)b * NPX + pxi) * 24 + ocb] = *(ushort4*)&hb;
                } else {
                    *(float4*)&yoF[((size_t)b * NPX + pxi) * 24 + ocb] =
                        make_float4(v0, v1, v2, v3);
                }
                ss[o][0] += v0; qq[o][0] += v0 * v0;
                ss[o][1] += v1; qq[o][1] += v1 * v1;
                ss[o][2] += v2; qq[o][2] += v2 * v2;
                ss[o][3] += v3; qq[o][3] += v3 * v3;
            }
        }
    }
#pragma unroll
    for (int o = 0; o < 2; o++) {
        int ocb = o * 16 + quad * 4;
#pragma unroll
        for (int r = 0; r < 4; r++) {
            float a = ss[o][r], q = qq[o][r];
            a += __shfl_xor(a, 1, 64); q += __shfl_xor(q, 1, 64);
            a += __shfl_xor(a, 2, 64); q += __shfl_xor(q, 2, 64);
            a += __shfl_xor(a, 4, 64); q += __shfl_xor(q, 4, 64);
            a += __shfl_xor(a, 8, 64); q += __shfl_xor(q, 8, 64);
            if (r16 == 0 && ocb < 24) {
                atomicAdd(&part[ocb + r], a);
                atomicAdd(&part[24 + ocb + r], q);
            }
        }
    }
    __syncthreads();
    if (tid < 48) atomicAdd(&stats[tid], part[tid]);
}

// ---------------- u/v precompute for g1 (bf16 output), BN4 computed in-kernel ----------------
__global__ __launch_bounds__(256) void uv_kernel(
    const float* __restrict__ y4t,
    const float* __restrict__ stp, const float* __restrict__ gam,
    const float* __restrict__ bet, float invN,
    const float* __restrict__ qst, const float* __restrict__ g1w,
    const float* __restrict__ g1b, u16* __restrict__ u, u16* __restrict__ v)
{
    int b = blockIdx.x, tid = threadIdx.x;
    __shared__ float xf[650];
    __shared__ float qv[11];
    __shared__ float scW[48];
    if (tid < 24) {
        float m   = stp[tid] * invN;
        float var = stp[24 + tid] * invN - m * m;
        float inv = gam[tid] * rsqrtf(var + 1e-5f);
        scW[tid]      = inv;
        scW[24 + tid] = bet[tid] - m * inv;
    }
    __syncthreads();
    for (int e = tid; e < 650; e += 256) {
        int o = e / 26, c = e % 26;
        float val;
        if (c < 24)      val = y4t[b * 600 + o * 24 + c] * scW[c] + scW[24 + c];
        else if (c == 24) val = (float)(o / 5 - 2) * 0.5f;
        else              val = (float)(o % 5 - 2) * 0.5f;
        xf[e] = val;
    }
    if (tid < 11) qv[tid] = qst[tid * MB + b];
    __syncthreads();
    const int n = tid;
    float wrow[63];
#pragma unroll
    for (int c = 0; c < 63; c++) wrow[c] = g1w[n * 63 + c];
    float qsum = g1b[n];
#pragma unroll
    for (int j = 0; j < 11; j++) qsum += wrow[52 + j] * qv[j];
    for (int o = 0; o < 25; o++) {
        float uu = 0.f, vv = qsum;
#pragma unroll
        for (int c = 0; c < 26; c++) {
            uu += wrow[c]      * xf[o * 26 + c];
            vv += wrow[26 + c] * xf[o * 26 + c];
        }
        u[(b * 25 + o) * 256 + n] = f2bf(uu);
        v[(b * 25 + o) * 256 + n] = f2bf(vv);
    }
}

// ---------------- fused g2/g3/g4 + pair-sum, bf16 MFMA, weights direct-from-global ----------------
__global__ __launch_bounds__(256, 2) void g_fused(
    const u16* __restrict__ u_bf, const u16* __restrict__ v_bf,
    const u16* __restrict__ wfrag,
    const float* __restrict__ b2, const float* __restrict__ b3, const float* __restrict__ b4,
    float* __restrict__ xg)
{
    __shared__ u16 hS[32768];   // 128 x 256 halves, XOR-swizzled 8-half granules
    const int tid  = threadIdx.x;
    const int b    = blockIdx.x / 5;
    const int p0   = (blockIdx.x % 5) * 128;
    const int lane = tid & 63, wave = tid >> 6;
    const int r16  = lane & 15, sub = lane >> 4;
    const int n0w  = wave * 64;

    const u16* wfL = wfrag + (size_t)(wave * 4) * 512 + (size_t)lane * 8;

    bf16x8 wcur[4], wnxt[4];
#pragma unroll
    for (int tn = 0; tn < 4; tn++)
        wcur[tn] = *(const bf16x8*)&wfL[(size_t)tn * 512];
#pragma unroll
    for (int tn = 0; tn < 4; tn++) wnxt[tn] = wcur[tn];

    {
        const int m = tid & 127, half = tid >> 7;
        const int p = p0 + m;
        if (p < 625) {
            const int oi = p % 25, ok = p / 25;
            const uint4* up = (const uint4*)(u_bf + (size_t)(b * 25 + oi) * 256);
            const uint4* vp = (const uint4*)(v_bf + (size_t)(b * 25 + ok) * 256);
#pragma unroll
            for (int gi = 0; gi < 16; gi++) {
                const int g = half * 16 + gi;
                uint4 ua = up[g], va = vp[g];
                bf16x8 ub = *(bf16x8*)&ua;
                bf16x8 vb = *(bf16x8*)&va;
                f32x8 uf = __builtin_convertvector(ub, f32x8);
                f32x8 vf = __builtin_convertvector(vb, f32x8);
                f32x8 hf = uf + vf;
                hf = __builtin_elementwise_max(hf, (f32x8)(0.f));
                bf16x8 hb = __builtin_convertvector(hf, bf16x8);
                *(uint4*)&hS[m * 256 + ((g ^ (m & 7)) * 8)] = *(uint4*)&hb;
            }
        } else {
            uint4 z = make_uint4(0, 0, 0, 0);
#pragma unroll
            for (int gi = 0; gi < 16; gi++) {
                const int g = half * 16 + gi;
                *(uint4*)&hS[m * 256 + ((g ^ (m & 7)) * 8)] = z;
            }
        }
    }

#pragma unroll 1
    for (int l = 0; l < 3; l++) {
        f32x4 acc[8][4];
#pragma unroll
        for (int tm = 0; tm < 8; tm++)
#pragma unroll
            for (int tn = 0; tn < 4; tn++)
                acc[tm][tn] = (f32x4)(0.f);

        __syncthreads();

#pragma unroll 1
        for (int kb = 0; kb < 8; kb++) {
            const int s = l * 8 + kb;
            if (s < 23) {
#pragma unroll
                for (int tn = 0; tn < 4; tn++)
                    wnxt[tn] = *(const bf16x8*)&wfL[((size_t)(s + 1) * 16 + tn) * 512];
            }
            bf16x8 bfr[8];
            const int g = kb * 4 + sub;
#pragma unroll
            for (int tm = 0; tm < 8; tm++) {
                const int m = tm * 16 + r16;
                bfr[tm] = *(const bf16x8*)&hS[m * 256 + ((g ^ (m & 7)) * 8)];
            }
#pragma unroll
            for (int tm = 0; tm < 8; tm++)
#pragma unroll
                for (int tn = 0; tn < 4; tn++)
                    acc[tm][tn] = __builtin_amdgcn_mfma_f32_16x16x32_bf16(
                        wcur[tn], bfr[tm], acc[tm][tn], 0, 0, 0);
#pragma unroll
            for (int tn = 0; tn < 4; tn++) wcur[tn] = wnxt[tn];
        }
        __syncthreads();

        const float* bl = (l == 0) ? b2 : ((l == 1) ? b3 : b4);
        if (l < 2) {
#pragma unroll
            for (int tn = 0; tn < 4; tn++) {
                const int n0 = n0w + tn * 16 + sub * 4;
                const float4 bb = *(const float4*)&bl[n0];
                const f32x4 bb4 = {bb.x, bb.y, bb.z, bb.w};
                const int gg = n0 >> 3;
                const int sh = (sub & 1) * 4;
#pragma unroll
                for (int tm = 0; tm < 8; tm++) {
                    const int m = tm * 16 + r16;
                    f32x4 t = acc[tm][tn] + bb4;
                    t = __builtin_elementwise_max(t, (f32x4)(0.f));
                    bf16x4 hb = __builtin_convertvector(t, bf16x4);
                    *(ushort4*)&hS[m * 256 + ((gg ^ (m & 7)) * 8) + sh] = *(ushort4*)&hb;
                }
            }
        } else {
            f32x4 sv[4];
#pragma unroll
            for (int tn = 0; tn < 4; tn++) sv[tn] = (f32x4)(0.f);
#pragma unroll
            for (int tn = 0; tn < 4; tn++) {
                const int n0 = n0w + tn * 16 + sub * 4;
                const float4 bb = *(const float4*)&bl[n0];
                const f32x4 bb4 = {bb.x, bb.y, bb.z, bb.w};
#pragma unroll
                for (int tm = 0; tm < 8; tm++) {
                    const int m = tm * 16 + r16;
                    if (p0 + m < 625) {
                        f32x4 t = acc[tm][tn] + bb4;
                        t = __builtin_elementwise_max(t, (f32x4)(0.f));
                        sv[tn] += t;
                    }
                }
            }
#pragma unroll
            for (int tn = 0; tn < 4; tn++)
#pragma unroll
                for (int r = 0; r < 4; r++) {
                    float v = sv[tn][r];
                    v += __shfl_xor(v, 1, 64);
                    v += __shfl_xor(v, 2, 64);
                    v += __shfl_xor(v, 4, 64);
                    v += __shfl_xor(v, 8, 64);
                    if (r16 == 0)
                        atomicAdd(&xg[b * 256 + n0w + tn * 16 + sub * 4 + r], v);
                }
        }
    }
}

// ---------------- f1 -> fc2 -> fc3 -> log_softmax ----------------
__global__ __launch_bounds__(256) void f_fused(
    const float* __restrict__ xg,
    const float* __restrict__ f1w, const float* __restrict__ f1b,
    const float* __restrict__ fc2w, const float* __restrict__ fc2b,
    const float* __restrict__ fc3w, const float* __restrict__ fc3b,
    float* __restrict__ out)
{
    const int b = blockIdx.x, tid = threadIdx.x;
    __shared__ float xa[256], xb[256], lg[10], red[2];
    xa[tid] = xg[b * 256 + tid];
    __syncthreads();
    {
        const float4* wr = (const float4*)(f1w + (size_t)tid * 256);
        float a = f1b[tid];
#pragma unroll
        for (int k4 = 0; k4 < 64; k4++) {
            float4 w4 = wr[k4];
            a += w4.x * xa[k4 * 4 + 0] + w4.y * xa[k4 * 4 + 1]
               + w4.z * xa[k4 * 4 + 2] + w4.w * xa[k4 * 4 + 3];
        }
        xb[tid] = a > 0.f ? a : 0.f;
    }
    __syncthreads();
    {
        const float4* wr = (const float4*)(fc2w + (size_t)tid * 256);
        float a = fc2b[tid];
#pragma unroll
        for (int k4 = 0; k4 < 64; k4++) {
            float4 w4 = wr[k4];
            a += w4.x * xb[k4 * 4 + 0] + w4.y * xb[k4 * 4 + 1]
               + w4.z * xb[k4 * 4 + 2] + w4.w * xb[k4 * 4 + 3];
        }
        __syncthreads();
        xa[tid] = a > 0.f ? a : 0.f;
    }
    __syncthreads();
    if (tid < 10) {
        const float4* wr = (const float4*)(fc3w + (size_t)tid * 256);
        float a = fc3b[tid];
#pragma unroll
        for (int k4 = 0; k4 < 64; k4++) {
            float4 w4 = wr[k4];
            a += w4.x * xa[k4 * 4 + 0] + w4.y * xa[k4 * 4 + 1]
               + w4.z * xa[k4 * 4 + 2] + w4.w * xa[k4 * 4 + 3];
        }
        lg[tid] = a;
    }
    __syncthreads();
    if (tid == 0) {
        float mx = lg[0];
        for (int o = 1; o < 10; o++) mx = lg[o] > mx ? lg[o] : mx;
        float ssum = 0.f;
        for (int o = 0; o < 10; o++) ssum += expf(lg[o] - mx);
        red[0] = mx;
        red[1] = logf(ssum);
    }
    __syncthreads();
    if (tid < 10) out[b * 10 + tid] = lg[tid] - red[0] - red[1];
}

// ---------------- launcher ----------------
extern "C" void kernel_launch(void* const* d_in, const int* in_sizes, int n_in,
                              void* d_out, int out_size, void* d_ws, size_t ws_size,
                              hipStream_t stream)
{
    const float* img  = (const float*)d_in[0];
    const float* qst  = (const float*)d_in[1];
    const float* cw1  = (const float*)d_in[2];
    const float* cb1  = (const float*)d_in[3];
    const float* bg1  = (const float*)d_in[4];
    const float* bb1  = (const float*)d_in[5];
    const float* cw2  = (const float*)d_in[6];
    const float* cb2  = (const float*)d_in[7];
    const float* bg2  = (const float*)d_in[8];
    const float* bb2  = (const float*)d_in[9];
    const float* cw3  = (const float*)d_in[10];
    const float* cb3  = (const float*)d_in[11];
    const float* bg3  = (const float*)d_in[12];
    const float* bb3  = (const float*)d_in[13];
    const float* cw4  = (const float*)d_in[14];
    const float* cb4  = (const float*)d_in[15];
    const float* bg4  = (const float*)d_in[16];
    const float* bb4  = (const float*)d_in[17];
    const float* g1w  = (const float*)d_in[18];
    const float* g1b  = (const float*)d_in[19];
    const float* g2w  = (const float*)d_in[20];
    const float* g2b  = (const float*)d_in[21];
    const float* g3w  = (const float*)d_in[22];
    const float* g3b  = (const float*)d_in[23];
    const float* g4w  = (const float*)d_in[24];
    const float* g4b  = (const float*)d_in[25];
    const float* f1w  = (const float*)d_in[26];
    const float* f1b  = (const float*)d_in[27];
    const float* fc2w = (const float*)d_in[28];
    const float* fc2b = (const float*)d_in[29];
    const float* fc3w = (const float*)d_in[30];
    const float* fc3b = (const float*)d_in[31];
    float* out = (float*)d_out;

    float* ws    = (float*)d_ws;
    float* stats = ws;                        // 192
    float* xg    = ws + 192;                  // 131072
    u16*   wfrag = (u16*)(ws + 131456);       // 196608 u16
    u16*   y1u   = (u16*)(ws + 328064);       // 19,660,800 u16 (bf16)
    u16*   y2u   = (u16*)(ws + 19988864);     // 4,915,200 u16 (bf16)
    float* y3    = ws + 24904064;             // 1,228,800   [b][100][24]
    float* y4    = ws + 26132864;             // 307,200     [b][25][24]
    u16*   u_bf  = (u16*)(ws + 26440064);     // 3,276,800 u16
    u16*   v_bf  = (u16*)(ws + 28078464);     // 3,276,800 u16
    float* wt1   = ws + 29716864;             // 648
    u16*   wcfrag = (u16*)(ws + 29717512);    // 27648 u16

    prep_all<<<879, 256, 0, stream>>>(g2w, g3w, g4w, wfrag,
                                      cw1, cw2, cw3, cw4, wt1, wcfrag,
                                      stats, xg);

    conv1_t<<<2048, 256, 0, stream>>>(img, wt1, cb1, y1u, stats);

    convM<40, 20, 4, 5, 1, 1><<<2560, 256, 0, stream>>>(
        (const void*)y1u, stats, bg1, bb1, 1.f / 819200.f, wcfrag, cb2,
        (void*)y2u, stats + 48);
    convM<20, 10, 10, 7, 1, 0><<<512, 256, 0, stream>>>(
        (const void*)y2u, stats + 48, bg2, bb2, 1.f / 204800.f, wcfrag + 9216, cb3,
        (void*)y3, stats + 96);
    convM<10, 5, 5, 2, 0, 0><<<512, 256, 0, stream>>>(
        (const void*)y3, stats + 96, bg3, bb3, 1.f / 51200.f, wcfrag + 18432, cb4,
        (void*)y4, stats + 144);

    uv_kernel<<<512, 256, 0, stream>>>(y4, stats + 144, bg4, bb4, 1.f / 12800.f,
                                       qst, g1w, g1b, u_bf, v_bf);

    g_fused<<<2560, 256, 0, stream>>>(u_bf, v_bf, wfrag, g2b, g3b, g4b, xg);

    f_fused<<<512, 256, 0, stream>>>(xg, f1w, f1b, fc2w, fc2b, fc3w, fc3b, out);
}

// Round 13
// 397.415 us; speedup vs baseline: 1.1933x; 1.1238x over previous
//
#include <hip/hip_runtime.h>
#include <math.h>

// ---------------- problem constants ----------------
#define MB    512
#define FS    24
#define QDIM  11
#define OBJ   25
#define HID   256
#define SG    64          // stats groups (atomic-contention spreading)

typedef unsigned short u16;
typedef __attribute__((ext_vector_type(8))) __bf16 bf16x8;
typedef __attribute__((ext_vector_type(4))) __bf16 bf16x4;
typedef __attribute__((ext_vector_type(4))) float f32x4;
typedef __attribute__((ext_vector_type(8))) float f32x8;

__device__ __forceinline__ float bf2f(u16 h) {
    return __uint_as_float(((unsigned int)h) << 16);
}
__device__ __forceinline__ u16 f2bf(float f) {
    unsigned int u = __float_as_uint(f);
    return (u16)((u + 0x7FFFu + ((u >> 16) & 1u)) >> 16);
}

// ---------------- combined prep (+ stats/xg zeroing; replaces memset dispatch) ----------------
__global__ __launch_bounds__(256) void prep_all(
    const float* __restrict__ g2w, const float* __restrict__ g3w,
    const float* __restrict__ g4w, u16* __restrict__ wfrag,
    const float* __restrict__ cw1, const float* __restrict__ cw2,
    const float* __restrict__ cw3, const float* __restrict__ cw4,
    float* __restrict__ wt1, u16* __restrict__ wcfrag,
    float* __restrict__ statsG, float* __restrict__ xg)
{
    // zeroing (consumers are in later dispatches; stream order guarantees visibility)
    if (blockIdx.x < 48) statsG[blockIdx.x * 256 + threadIdx.x] = 0.f;  // 4 layers x 64 grp x 48
    if (blockIdx.x < 512) xg[blockIdx.x * 256 + threadIdx.x] = 0.f;

    if (blockIdx.x < 768) {
        int idx = blockIdx.x * 256 + threadIdx.x;   // 196608 total
        int jj = idx & 7;
        int lane = (idx >> 3) & 63;
        int tn = (idx >> 9) & 15;
        int c = (idx >> 13) & 7;
        int l = idx >> 16;
        const float* W = (l == 0) ? g2w : ((l == 1) ? g3w : g4w);
        int n = tn * 16 + (lane & 15);
        int k = c * 32 + (lane >> 4) * 8 + jj;
        wfrag[idx] = f2bf(W[n * 256 + k]);
    } else {
        int idx = (blockIdx.x - 768) * 256 + threadIdx.x;
        if (idx < 648) {
            int k = idx / 24, oc = idx % 24;
            wt1[idx] = cw1[oc * 27 + k];
        } else if (idx < 648 + 27648) {
            int t = idx - 648;
            int l = t / 9216, r = t % 9216;
            int cell = r / 1024, rr = r % 1024;
            int o = rr / 512, q = rr % 512;
            int lane = q / 8, j = q % 8;
            int oc = o * 16 + (lane & 15);
            int ic = (lane >> 4) * 8 + j;
            const float* w = (l == 0) ? cw2 : ((l == 1) ? cw3 : cw4);
            u16 v = 0;
            if (oc < 24 && ic < 24) v = f2bf(w[oc * 216 + ic * 9 + cell]);
            wcfrag[t] = v;
        }
    }
}

// ---------------- conv1: img NCHW -> y1 channel-last (bf16) + fused BN stats.
// Two pixels per thread; grouped-atomic stats tail. ----------------
__global__ __launch_bounds__(256) void conv1_t(
    const float* __restrict__ img, const float* __restrict__ wt1,
    const float* __restrict__ bias, u16* __restrict__ yout,
    float* __restrict__ stats)
{
    __shared__ float tile[3 * 21 * 85];
    __shared__ float part[48];
    const int tid = threadIdx.x;
    const int b   = blockIdx.x >> 2;
    const int y0  = (blockIdx.x & 3) * 10;
    const int grp = blockIdx.x & (SG - 1);
    const int iy_base = 2 * y0 - 1;
    for (int e = tid; e < 3 * 21 * 85; e += 256) {
        int ixt = e % 85; int rem = e / 85;
        int iyl = rem % 21; int ic = rem / 21;
        int iy = iy_base + iyl, ix = ixt - 1;
        float v = 0.f;
        if ((unsigned)iy < 80u && (unsigned)ix < 80u)
            v = img[((size_t)(b * 3 + ic) * 80 + iy) * 80 + ix];
        tile[e] = v;
    }
    if (tid < 48) part[tid] = 0.f;
    __syncthreads();

    // pixel 0: tid (always < 400); pixel 1: tid + 256 (active if tid < 144)
    const int px0 = tid;
    const bool act1 = tid < 144;
    const int px1 = act1 ? (tid + 256) : tid;
    const int yl0 = px0 / 40, x0 = px0 % 40;
    const int yl1 = px1 / 40, x1 = px1 % 40;

    float acc0[24], acc1[24];
#pragma unroll
    for (int oc = 0; oc < 24; oc++) { acc0[oc] = bias[oc]; acc1[oc] = acc0[oc]; }

#pragma unroll 1
    for (int ic = 0; ic < 3; ic++) {
#pragma unroll 1
        for (int ky = 0; ky < 3; ky++) {
#pragma unroll
            for (int kx = 0; kx < 3; kx++) {
                const int k = (ic * 3 + ky) * 3 + kx;
                float xin0 = tile[ic * 1785 + (2 * yl0 + ky) * 85 + (2 * x0 + kx)];
                float xin1 = tile[ic * 1785 + (2 * yl1 + ky) * 85 + (2 * x1 + kx)];
                const float4* wrow = (const float4*)&wt1[k * 24];
#pragma unroll
                for (int g = 0; g < 6; g++) {
                    float4 wv = wrow[g];
                    acc0[g * 4 + 0] = fmaf(xin0, wv.x, acc0[g * 4 + 0]);
                    acc0[g * 4 + 1] = fmaf(xin0, wv.y, acc0[g * 4 + 1]);
                    acc0[g * 4 + 2] = fmaf(xin0, wv.z, acc0[g * 4 + 2]);
                    acc0[g * 4 + 3] = fmaf(xin0, wv.w, acc0[g * 4 + 3]);
                    acc1[g * 4 + 0] = fmaf(xin1, wv.x, acc1[g * 4 + 0]);
                    acc1[g * 4 + 1] = fmaf(xin1, wv.y, acc1[g * 4 + 1]);
                    acc1[g * 4 + 2] = fmaf(xin1, wv.z, acc1[g * 4 + 2]);
                    acc1[g * 4 + 3] = fmaf(xin1, wv.w, acc1[g * 4 + 3]);
                }
            }
        }
    }

#pragma unroll
    for (int oc = 0; oc < 24; oc++) {
        acc0[oc] = fmaxf(acc0[oc], 0.f);
        acc1[oc] = act1 ? fmaxf(acc1[oc], 0.f) : 0.f;
    }
    {
        u16* op = &yout[((size_t)b * 1600 + (y0 + yl0) * 40 + x0) * 24];
#pragma unroll
        for (int g = 0; g < 3; g++) {
            f32x8 t = {acc0[g * 8 + 0], acc0[g * 8 + 1], acc0[g * 8 + 2], acc0[g * 8 + 3],
                       acc0[g * 8 + 4], acc0[g * 8 + 5], acc0[g * 8 + 6], acc0[g * 8 + 7]};
            bf16x8 hb = __builtin_convertvector(t, bf16x8);
            *(uint4*)&op[g * 8] = *(uint4*)&hb;
        }
    }
    if (act1) {
        u16* op = &yout[((size_t)b * 1600 + (y0 + yl1) * 40 + x1) * 24];
#pragma unroll
        for (int g = 0; g < 3; g++) {
            f32x8 t = {acc1[g * 8 + 0], acc1[g * 8 + 1], acc1[g * 8 + 2], acc1[g * 8 + 3],
                       acc1[g * 8 + 4], acc1[g * 8 + 5], acc1[g * 8 + 6], acc1[g * 8 + 7]};
            bf16x8 hb = __builtin_convertvector(t, bf16x8);
            *(uint4*)&op[g * 8] = *(uint4*)&hb;
        }
    }

    // halving-tree wave reduction of 48 stats: 96 shfl.
    {
        float v[48];
#pragma unroll
        for (int oc = 0; oc < 24; oc++) {
            v[oc] = acc0[oc] + acc1[oc];
            v[24 + oc] = acc0[oc] * acc0[oc] + acc1[oc] * acc1[oc];
        }
        const int ln = tid & 63;
#pragma unroll
        for (int i = 0; i < 48; i++) v[i] += __shfl_xor(v[i], 1, 64);
        {
            const bool bs = (ln & 1) != 0;
#pragma unroll
            for (int i = 0; i < 24; i++) v[i] = bs ? v[24 + i] : v[i];
        }
#pragma unroll
        for (int i = 0; i < 24; i++) v[i] += __shfl_xor(v[i], 2, 64);
        {
            const bool bs = (ln & 2) != 0;
#pragma unroll
            for (int i = 0; i < 12; i++) v[i] = bs ? v[12 + i] : v[i];
        }
#pragma unroll
        for (int i = 0; i < 12; i++) v[i] += __shfl_xor(v[i], 4, 64);
        {
            const bool bs = (ln & 4) != 0;
#pragma unroll
            for (int i = 0; i < 6; i++) v[i] = bs ? v[6 + i] : v[i];
        }
#pragma unroll
        for (int i = 0; i < 6; i++) v[i] += __shfl_xor(v[i], 8, 64);
        {
            const bool bs = (ln & 8) != 0;
#pragma unroll
            for (int i = 0; i < 3; i++) v[i] = bs ? v[3 + i] : v[i];
        }
#pragma unroll
        for (int i = 0; i < 3; i++) {
            v[i] += __shfl_xor(v[i], 16, 64);
            v[i] += __shfl_xor(v[i], 32, 64);
        }
        if (ln < 16) {
            const int base = (ln & 1) * 24 + ((ln >> 1) & 1) * 12
                           + ((ln >> 2) & 1) * 6 + ((ln >> 3) & 1) * 3;
#pragma unroll
            for (int i = 0; i < 3; i++) atomicAdd(&part[base + i], v[i]);
        }
    }
    __syncthreads();
    if (tid < 48) atomicAdd(&stats[grp * 48 + tid], part[tid]);
}

// ---------------- MFMA conv 24->24 stride2 pad1, channel-last, BN(prev, 64-group) folded on read,
//                  bf16-in / bf16-out switchable, + fused bias/relu/store/grouped-stats ----------------
template<int HIN, int HOUT, int YT, int MT, int INBF, int OUTBF>
__global__ __launch_bounds__(256) void convM(
    const void* __restrict__ yin,
    const float* __restrict__ stp, const float* __restrict__ gam,
    const float* __restrict__ bet, float invN,
    const u16* __restrict__ wcf_g,
    const float* __restrict__ bias,
    void* __restrict__ yout, float* __restrict__ stats)
{
    constexpr int ROWS = 2 * YT + 1;
    constexpr int R    = 2 * HOUT + 1;
    constexpr int POS  = ROWS * R;
    constexpr int NPX  = HOUT * HOUT;
    constexpr int NPXB = YT * HOUT;
    constexpr int TILES = HOUT / YT;
    constexpr int MTPW = (MT + 3) / 4;
    __shared__ __align__(16) u16 tile[POS * 24 + 16];
    __shared__ float scW[48];
    __shared__ float part[48];
    const int tid  = threadIdx.x;
    const int b    = (TILES == 1) ? blockIdx.x : (int)(blockIdx.x / TILES);
    const int y0   = (TILES == 1) ? 0 : (int)(blockIdx.x % TILES) * YT;
    const int grp  = blockIdx.x & (SG - 1);
    const int lane = tid & 63, wave = tid >> 6;
    const int r16  = lane & 15, quad = lane >> 4;

    const float* yinF = (const float*)yin;
    const u16*   yinH = (const u16*)yin;
    float* yoF = (float*)yout;
    u16*   yoH = (u16*)yout;

    if (tid < 24) {
        float s0 = 0.f, s1 = 0.f;
#pragma unroll 8
        for (int g2 = 0; g2 < SG; g2++) {
            s0 += stp[g2 * 48 + tid];
            s1 += stp[g2 * 48 + 24 + tid];
        }
        float m   = s0 * invN;
        float var = s1 * invN - m * m;
        float inv = gam[tid] * rsqrtf(var + 1e-5f);
        scW[tid]      = inv;
        scW[24 + tid] = bet[tid] - m * inv;
    }
    if (tid < 48) part[tid] = 0.f;

    // weight A-fragments -> registers (per lane)
    bf16x8 wcf[9][2];
#pragma unroll
    for (int c = 0; c < 9; c++)
#pragma unroll
        for (int o = 0; o < 2; o++)
            wcf[c][o] = *(const bf16x8*)&wcf_g[((c * 2 + o) * 64 + lane) * 8];

    __syncthreads();   // scW ready

    // hoist BN scale/shift to registers (vector form)
    f32x8 scv[3], ofv[3];
#pragma unroll
    for (int g = 0; g < 3; g++)
#pragma unroll
        for (int c2 = 0; c2 < 8; c2++) {
            scv[g][c2] = scW[g * 8 + c2];
            ofv[g][c2] = scW[24 + g * 8 + c2];
        }

    // stage input tile (bf16, channel-last, BN-folded)
    const int iy_base = 2 * y0 - 1;
    for (int p = tid; p < POS; p += 256) {
        int iyl = p / R, ixt = p % R;
        int iy = iy_base + iyl, ix = ixt - 1;
        if ((unsigned)iy < (unsigned)HIN && (unsigned)ix < (unsigned)HIN) {
            const size_t base = ((size_t)b * HIN * HIN + iy * HIN + ix) * 24;
            if constexpr (INBF) {
                const uint4* ip4 = (const uint4*)(yinH + base);
#pragma unroll
                for (int g = 0; g < 3; g++) {
                    uint4 raw = ip4[g];
                    bf16x8 hv = *(bf16x8*)&raw;
                    f32x8 xv = __builtin_convertvector(hv, f32x8);
                    f32x8 r = xv * scv[g] + ofv[g];
                    bf16x8 hb = __builtin_convertvector(r, bf16x8);
                    *(uint4*)&tile[p * 24 + g * 8] = *(uint4*)&hb;
                }
            } else {
                const float4* ip4 = (const float4*)(yinF + base);
#pragma unroll
                for (int g = 0; g < 3; g++) {
                    float4 A = ip4[g * 2], B = ip4[g * 2 + 1];
                    f32x8 xv = {A.x, A.y, A.z, A.w, B.x, B.y, B.z, B.w};
                    f32x8 r = xv * scv[g] + ofv[g];
                    bf16x8 hb = __builtin_convertvector(r, bf16x8);
                    *(uint4*)&tile[p * 24 + g * 8] = *(uint4*)&hb;
                }
            }
        } else {
            uint4 z = make_uint4(0, 0, 0, 0);
#pragma unroll
            for (int g = 0; g < 3; g++)
                *(uint4*)&tile[p * 24 + g * 8] = z;
        }
    }
    __syncthreads();

    f32x4 acc[MTPW][2];
#pragma unroll
    for (int t = 0; t < MTPW; t++) {
        acc[t][0] = (f32x4)(0.f);
        acc[t][1] = (f32x4)(0.f);
    }

    int baseT[MTPW];
#pragma unroll
    for (int t = 0; t < MTPW; t++) {
        int mt = wave + t * 4;
        int pxl = mt * 16 + r16;
        if (pxl > NPXB - 1) pxl = NPXB - 1;
        baseT[t] = ((2 * (pxl / HOUT)) * R + 2 * (pxl % HOUT)) * 24 + quad * 8;
    }

#pragma unroll
    for (int ky = 0; ky < 3; ky++) {
#pragma unroll
        for (int kx = 0; kx < 3; kx++) {
            const int cell = ky * 3 + kx;
            const int coff = (ky * R + kx) * 24;
            bf16x8 xf[MTPW];
#pragma unroll
            for (int t = 0; t < MTPW; t++) {
                int mt = wave + t * 4;
                uint4 tmp = make_uint4(0, 0, 0, 0);
                if (mt < MT && quad < 3)
                    tmp = *(const uint4*)&tile[baseT[t] + coff];
                xf[t] = *(bf16x8*)&tmp;
            }
#pragma unroll
            for (int t = 0; t < MTPW; t++) {
                int mt = wave + t * 4;
                if (mt < MT) {
                    acc[t][0] = __builtin_amdgcn_mfma_f32_16x16x32_bf16(
                        wcf[cell][0], xf[t], acc[t][0], 0, 0, 0);
                    acc[t][1] = __builtin_amdgcn_mfma_f32_16x16x32_bf16(
                        wcf[cell][1], xf[t], acc[t][1], 0, 0, 0);
                }
            }
        }
    }

    // epilogue: bias + relu + store + stats
    float ss[2][4], qq[2][4];
#pragma unroll
    for (int o = 0; o < 2; o++)
#pragma unroll
        for (int r = 0; r < 4; r++) { ss[o][r] = 0.f; qq[o][r] = 0.f; }

#pragma unroll
    for (int t = 0; t < MTPW; t++) {
        int mt = wave + t * 4;
        if (mt >= MT) continue;
        int pxl = mt * 16 + r16;
        bool pv = pxl < NPXB;
        int pxi = y0 * HOUT + pxl;
#pragma unroll
        for (int o = 0; o < 2; o++) {
            int ocb = o * 16 + quad * 4;
            if (pv && ocb < 24) {
                float4 bb = *(const float4*)&bias[ocb];
                float v0 = fmaxf(acc[t][o][0] + bb.x, 0.f);
                float v1 = fmaxf(acc[t][o][1] + bb.y, 0.f);
                float v2 = fmaxf(acc[t][o][2] + bb.z, 0.f);
                float v3 = fmaxf(acc[t][o][3] + bb.w, 0.f);
                if constexpr (OUTBF) {
                    f32x4 tv = {v0, v1, v2, v3};
                    bf16x4 hb = __builtin_convertvector(tv, bf16x4);
                    *(ushort4*)&yoH[((size_t)b * NPX + pxi) * 24 + ocb] = *(ushort4*)&hb;
                } else {
                    *(float4*)&yoF[((size_t)b * NPX + pxi) * 24 + ocb] =
                        make_float4(v0, v1, v2, v3);
                }
                ss[o][0] += v0; qq[o][0] += v0 * v0;
                ss[o][1] += v1; qq[o][1] += v1 * v1;
                ss[o][2] += v2; qq[o][2] += v2 * v2;
                ss[o][3] += v3; qq[o][3] += v3 * v3;
            }
        }
    }
#pragma unroll
    for (int o = 0; o < 2; o++) {
        int ocb = o * 16 + quad * 4;
#pragma unroll
        for (int r = 0; r < 4; r++) {
            float a = ss[o][r], q = qq[o][r];
            a += __shfl_xor(a, 1, 64); q += __shfl_xor(q, 1, 64);
            a += __shfl_xor(a, 2, 64); q += __shfl_xor(q, 2, 64);
            a += __shfl_xor(a, 4, 64); q += __shfl_xor(q, 4, 64);
            a += __shfl_xor(a, 8, 64); q += __shfl_xor(q, 8, 64);
            if (r16 == 0 && ocb < 24) {
                atomicAdd(&part[ocb + r], a);
                atomicAdd(&part[24 + ocb + r], q);
            }
        }
    }
    __syncthreads();
    if (tid < 48) atomicAdd(&stats[grp * 48 + tid], part[tid]);
}

// ---------------- u/v precompute for g1 (bf16 output), BN4 (64-group) computed in-kernel ----------------
__global__ __launch_bounds__(256) void uv_kernel(
    const float* __restrict__ y4t,
    const float* __restrict__ stp, const float* __restrict__ gam,
    const float* __restrict__ bet, float invN,
    const float* __restrict__ qst, const float* __restrict__ g1w,
    const float* __restrict__ g1b, u16* __restrict__ u, u16* __restrict__ v)
{
    int b = blockIdx.x, tid = threadIdx.x;
    __shared__ float xf[650];
    __shared__ float qv[11];
    __shared__ float scW[48];
    if (tid < 24) {
        float s0 = 0.f, s1 = 0.f;
#pragma unroll 8
        for (int g2 = 0; g2 < SG; g2++) {
            s0 += stp[g2 * 48 + tid];
            s1 += stp[g2 * 48 + 24 + tid];
        }
        float m   = s0 * invN;
        float var = s1 * invN - m * m;
        float inv = gam[tid] * rsqrtf(var + 1e-5f);
        scW[tid]      = inv;
        scW[24 + tid] = bet[tid] - m * inv;
    }
    __syncthreads();
    for (int e = tid; e < 650; e += 256) {
        int o = e / 26, c = e % 26;
        float val;
        if (c < 24)      val = y4t[b * 600 + o * 24 + c] * scW[c] + scW[24 + c];
        else if (c == 24) val = (float)(o / 5 - 2) * 0.5f;
        else              val = (float)(o % 5 - 2) * 0.5f;
        xf[e] = val;
    }
    if (tid < 11) qv[tid] = qst[tid * MB + b];
    __syncthreads();
    const int n = tid;
    float wrow[63];
#pragma unroll
    for (int c = 0; c < 63; c++) wrow[c] = g1w[n * 63 + c];
    float qsum = g1b[n];
#pragma unroll
    for (int j = 0; j < 11; j++) qsum += wrow[52 + j] * qv[j];
    for (int o = 0; o < 25; o++) {
        float uu = 0.f, vv = qsum;
#pragma unroll
        for (int c = 0; c < 26; c++) {
            uu += wrow[c]      * xf[o * 26 + c];
            vv += wrow[26 + c] * xf[o * 26 + c];
        }
        u[(b * 25 + o) * 256 + n] = f2bf(uu);
        v[(b * 25 + o) * 256 + n] = f2bf(vv);
    }
}

// ---------------- fused g2/g3/g4 + pair-sum, bf16 MFMA, weights direct-from-global ----------------
__global__ __launch_bounds__(256, 2) void g_fused(
    const u16* __restrict__ u_bf, const u16* __restrict__ v_bf,
    const u16* __restrict__ wfrag,
    const float* __restrict__ b2, const float* __restrict__ b3, const float* __restrict__ b4,
    float* __restrict__ xg)
{
    __shared__ u16 hS[32768];   // 128 x 256 halves, XOR-swizzled 8-half granules
    const int tid  = threadIdx.x;
    const int b    = blockIdx.x / 5;
    const int p0   = (blockIdx.x % 5) * 128;
    const int lane = tid & 63, wave = tid >> 6;
    const int r16  = lane & 15, sub = lane >> 4;
    const int n0w  = wave * 64;

    const u16* wfL = wfrag + (size_t)(wave * 4) * 512 + (size_t)lane * 8;

    bf16x8 wcur[4], wnxt[4];
#pragma unroll
    for (int tn = 0; tn < 4; tn++)
        wcur[tn] = *(const bf16x8*)&wfL[(size_t)tn * 512];
#pragma unroll
    for (int tn = 0; tn < 4; tn++) wnxt[tn] = wcur[tn];

    {
        const int m = tid & 127, half = tid >> 7;
        const int p = p0 + m;
        if (p < 625) {
            const int oi = p % 25, ok = p / 25;
            const uint4* up = (const uint4*)(u_bf + (size_t)(b * 25 + oi) * 256);
            const uint4* vp = (const uint4*)(v_bf + (size_t)(b * 25 + ok) * 256);
#pragma unroll
            for (int gi = 0; gi < 16; gi++) {
                const int g = half * 16 + gi;
                uint4 ua = up[g], va = vp[g];
                bf16x8 ub = *(bf16x8*)&ua;
                bf16x8 vb = *(bf16x8*)&va;
                f32x8 uf = __builtin_convertvector(ub, f32x8);
                f32x8 vf = __builtin_convertvector(vb, f32x8);
                f32x8 hf = uf + vf;
                hf = __builtin_elementwise_max(hf, (f32x8)(0.f));
                bf16x8 hb = __builtin_convertvector(hf, bf16x8);
                *(uint4*)&hS[m * 256 + ((g ^ (m & 7)) * 8)] = *(uint4*)&hb;
            }
        } else {
            uint4 z = make_uint4(0, 0, 0, 0);
#pragma unroll
            for (int gi = 0; gi < 16; gi++) {
                const int g = half * 16 + gi;
                *(uint4*)&hS[m * 256 + ((g ^ (m & 7)) * 8)] = z;
            }
        }
    }

#pragma unroll 1
    for (int l = 0; l < 3; l++) {
        f32x4 acc[8][4];
#pragma unroll
        for (int tm = 0; tm < 8; tm++)
#pragma unroll
            for (int tn = 0; tn < 4; tn++)
                acc[tm][tn] = (f32x4)(0.f);

        __syncthreads();

#pragma unroll 1
        for (int kb = 0; kb < 8; kb++) {
            const int s = l * 8 + kb;
            if (s < 23) {
#pragma unroll
                for (int tn = 0; tn < 4; tn++)
                    wnxt[tn] = *(const bf16x8*)&wfL[((size_t)(s + 1) * 16 + tn) * 512];
            }
            bf16x8 bfr[8];
            const int g = kb * 4 + sub;
#pragma unroll
            for (int tm = 0; tm < 8; tm++) {
                const int m = tm * 16 + r16;
                bfr[tm] = *(const bf16x8*)&hS[m * 256 + ((g ^ (m & 7)) * 8)];
            }
#pragma unroll
            for (int tm = 0; tm < 8; tm++)
#pragma unroll
                for (int tn = 0; tn < 4; tn++)
                    acc[tm][tn] = __builtin_amdgcn_mfma_f32_16x16x32_bf16(
                        wcur[tn], bfr[tm], acc[tm][tn], 0, 0, 0);
#pragma unroll
            for (int tn = 0; tn < 4; tn++) wcur[tn] = wnxt[tn];
        }
        __syncthreads();

        const float* bl = (l == 0) ? b2 : ((l == 1) ? b3 : b4);
        if (l < 2) {
#pragma unroll
            for (int tn = 0; tn < 4; tn++) {
                const int n0 = n0w + tn * 16 + sub * 4;
                const float4 bb = *(const float4*)&bl[n0];
                const f32x4 bb4 = {bb.x, bb.y, bb.z, bb.w};
                const int gg = n0 >> 3;
                const int sh = (sub & 1) * 4;
#pragma unroll
                for (int tm = 0; tm < 8; tm++) {
                    const int m = tm * 16 + r16;
                    f32x4 t = acc[tm][tn] + bb4;
                    t = __builtin_elementwise_max(t, (f32x4)(0.f));
                    bf16x4 hb = __builtin_convertvector(t, bf16x4);
                    *(ushort4*)&hS[m * 256 + ((gg ^ (m & 7)) * 8) + sh] = *(ushort4*)&hb;
                }
            }
        } else {
            f32x4 sv[4];
#pragma unroll
            for (int tn = 0; tn < 4; tn++) sv[tn] = (f32x4)(0.f);
#pragma unroll
            for (int tn = 0; tn < 4; tn++) {
                const int n0 = n0w + tn * 16 + sub * 4;
                const float4 bb = *(const float4*)&bl[n0];
                const f32x4 bb4 = {bb.x, bb.y, bb.z, bb.w};
#pragma unroll
                for (int tm = 0; tm < 8; tm++) {
                    const int m = tm * 16 + r16;
                    if (p0 + m < 625) {
                        f32x4 t = acc[tm][tn] + bb4;
                        t = __builtin_elementwise_max(t, (f32x4)(0.f));
                        sv[tn] += t;
                    }
                }
            }
#pragma unroll
            for (int tn = 0; tn < 4; tn++)
#pragma unroll
                for (int r = 0; r < 4; r++) {
                    float v = sv[tn][r];
                    v += __shfl_xor(v, 1, 64);
                    v += __shfl_xor(v, 2, 64);
                    v += __shfl_xor(v, 4, 64);
                    v += __shfl_xor(v, 8, 64);
                    if (r16 == 0)
                        atomicAdd(&xg[b * 256 + n0w + tn * 16 + sub * 4 + r], v);
                }
        }
    }
}

// ---------------- f1 -> fc2 -> fc3 -> log_softmax ----------------
__global__ __launch_bounds__(256) void f_fused(
    const float* __restrict__ xg,
    const float* __restrict__ f1w, const float* __restrict__ f1b,
    const float* __restrict__ fc2w, const float* __restrict__ fc2b,
    const float* __restrict__ fc3w, const float* __restrict__ fc3b,
    float* __restrict__ out)
{
    const int b = blockIdx.x, tid = threadIdx.x;
    __shared__ float xa[256], xb[256], lg[10], red[2];
    xa[tid] = xg[b * 256 + tid];
    __syncthreads();
    {
        const float4* wr = (const float4*)(f1w + (size_t)tid * 256);
        float a = f1b[tid];
#pragma unroll
        for (int k4 = 0; k4 < 64; k4++) {
            float4 w4 = wr[k4];
            a += w4.x * xa[k4 * 4 + 0] + w4.y * xa[k4 * 4 + 1]
               + w4.z * xa[k4 * 4 + 2] + w4.w * xa[k4 * 4 + 3];
        }
        xb[tid] = a > 0.f ? a : 0.f;
    }
    __syncthreads();
    {
        const float4* wr = (const float4*)(fc2w + (size_t)tid * 256);
        float a = fc2b[tid];
#pragma unroll
        for (int k4 = 0; k4 < 64; k4++) {
            float4 w4 = wr[k4];
            a += w4.x * xb[k4 * 4 + 0] + w4.y * xb[k4 * 4 + 1]
               + w4.z * xb[k4 * 4 + 2] + w4.w * xb[k4 * 4 + 3];
        }
        __syncthreads();
        xa[tid] = a > 0.f ? a : 0.f;
    }
    __syncthreads();
    if (tid < 10) {
        const float4* wr = (const float4*)(fc3w + (size_t)tid * 256);
        float a = fc3b[tid];
#pragma unroll
        for (int k4 = 0; k4 < 64; k4++) {
            float4 w4 = wr[k4];
            a += w4.x * xa[k4 * 4 + 0] + w4.y * xa[k4 * 4 + 1]
               + w4.z * xa[k4 * 4 + 2] + w4.w * xa[k4 * 4 + 3];
        }
        lg[tid] = a;
    }
    __syncthreads();
    if (tid == 0) {
        float mx = lg[0];
        for (int o = 1; o < 10; o++) mx = lg[o] > mx ? lg[o] : mx;
        float ssum = 0.f;
        for (int o = 0; o < 10; o++) ssum += expf(lg[o] - mx);
        red[0] = mx;
        red[1] = logf(ssum);
    }
    __syncthreads();
    if (tid < 10) out[b * 10 + tid] = lg[tid] - red[0] - red[1];
}

// ---------------- launcher ----------------
extern "C" void kernel_launch(void* const* d_in, const int* in_sizes, int n_in,
                              void* d_out, int out_size, void* d_ws, size_t ws_size,
                              hipStream_t stream)
{
    const float* img  = (const float*)d_in[0];
    const float* qst  = (const float*)d_in[1];
    const float* cw1  = (const float*)d_in[2];
    const float* cb1  = (const float*)d_in[3];
    const float* bg1  = (const float*)d_in[4];
    const float* bb1  = (const float*)d_in[5];
    const float* cw2  = (const float*)d_in[6];
    const float* cb2  = (const float*)d_in[7];
    const float* bg2  = (const float*)d_in[8];
    const float* bb2  = (const float*)d_in[9];
    const float* cw3  = (const float*)d_in[10];
    const float* cb3  = (const float*)d_in[11];
    const float* bg3  = (const float*)d_in[12];
    const float* bb3  = (const float*)d_in[13];
    const float* cw4  = (const float*)d_in[14];
    const float* cb4  = (const float*)d_in[15];
    const float* bg4  = (const float*)d_in[16];
    const float* bb4  = (const float*)d_in[17];
    const float* g1w  = (const float*)d_in[18];
    const float* g1b  = (const float*)d_in[19];
    const float* g2w  = (const float*)d_in[20];
    const float* g2b  = (const float*)d_in[21];
    const float* g3w  = (const float*)d_in[22];
    const float* g3b  = (const float*)d_in[23];
    const float* g4w  = (const float*)d_in[24];
    const float* g4b  = (const float*)d_in[25];
    const float* f1w  = (const float*)d_in[26];
    const float* f1b  = (const float*)d_in[27];
    const float* fc2w = (const float*)d_in[28];
    const float* fc2b = (const float*)d_in[29];
    const float* fc3w = (const float*)d_in[30];
    const float* fc3b = (const float*)d_in[31];
    float* out = (float*)d_out;

    float* ws    = (float*)d_ws;
    float* xg    = ws + 192;                  // 131072
    u16*   wfrag = (u16*)(ws + 131456);       // 196608 u16
    u16*   y1u   = (u16*)(ws + 328064);       // 19,660,800 u16 (bf16)
    u16*   y2u   = (u16*)(ws + 19988864);     // 4,915,200 u16 (bf16)
    float* y3    = ws + 24904064;             // 1,228,800   [b][100][24]
    float* y4    = ws + 26132864;             // 307,200     [b][25][24]
    u16*   u_bf  = (u16*)(ws + 26440064);     // 3,276,800 u16
    u16*   v_bf  = (u16*)(ws + 28078464);     // 3,276,800 u16
    float* wt1   = ws + 29716864;             // 648
    u16*   wcfrag = (u16*)(ws + 29717512);    // 27648 u16 (= 13824 floats, ends 29731336)
    float* statsG = ws + 29731392;            // 4 layers x 64 grp x 48 = 12288 floats

    prep_all<<<879, 256, 0, stream>>>(g2w, g3w, g4w, wfrag,
                                      cw1, cw2, cw3, cw4, wt1, wcfrag,
                                      statsG, xg);

    conv1_t<<<2048, 256, 0, stream>>>(img, wt1, cb1, y1u, statsG);

    convM<40, 20, 4, 5, 1, 1><<<2560, 256, 0, stream>>>(
        (const void*)y1u, statsG, bg1, bb1, 1.f / 819200.f, wcfrag, cb2,
        (void*)y2u, statsG + 3072);
    convM<20, 10, 10, 7, 1, 0><<<512, 256, 0, stream>>>(
        (const void*)y2u, statsG + 3072, bg2, bb2, 1.f / 204800.f, wcfrag + 9216, cb3,
        (void*)y3, statsG + 6144);
    convM<10, 5, 5, 2, 0, 0><<<512, 256, 0, stream>>>(
        (const void*)y3, statsG + 6144, bg3, bb3, 1.f / 51200.f, wcfrag + 18432, cb4,
        (void*)y4, statsG + 9216);

    uv_kernel<<<512, 256, 0, stream>>>(y4, statsG + 9216, bg4, bb4, 1.f / 12800.f,
                                       qst, g1w, g1b, u_bf, v_bf);

    g_fused<<<2560, 256, 0, stream>>>(u_bf, v_bf, wfrag, g2b, g3b, g4b, xg);

    f_fused<<<512, 256, 0, stream>>>(xg, f1w, f1b, fc2w, fc2b, fc3w, fc3b, out);
}